// Round 6
// baseline (735.355 us; speedup 1.0000x reference)
//
#include <hip/hip_runtime.h>
#include <hip/hip_bf16.h>
#include <cstddef>

typedef __attribute__((ext_vector_type(8))) short short8v;   // 8 x bf16 = 4 VGPR
typedef __attribute__((ext_vector_type(4))) float f32x4;     // MFMA accumulator

__device__ inline ushort f2bf(float f) {                     // f32 -> bf16 RNE
    uint u = __float_as_uint(f);
    uint r = (u + 0x7fffu + ((u >> 16) & 1u)) >> 16;
    return (ushort)r;
}
__device__ inline float bflo(uint v) { return __uint_as_float(v << 16); }
__device__ inline float bfhi(uint v) { return __uint_as_float(v & 0xffff0000u); }

// ---------------------------------------------------------------------------
// cast f32 -> bf16, 4 elements/thread
// ---------------------------------------------------------------------------
__global__ __launch_bounds__(256) void cast_bf16_kernel(
    const float* __restrict__ in, ushort* __restrict__ out, int n4)
{
    int i = blockIdx.x * 256 + threadIdx.x;
    if (i >= n4) return;
    float4 v = ((const float4*)in)[i];
    ushort4 o = { f2bf(v.x), f2bf(v.y), f2bf(v.z), f2bf(v.w) };
    ((ushort4*)out)[i] = o;
}

// ---------------------------------------------------------------------------
// W[K][Nout] f32  ->  Wt[rows][K] bf16  (rows >= Nout, zero-padded)
// ---------------------------------------------------------------------------
__global__ __launch_bounds__(256) void wtrans_kernel(
    const float* __restrict__ W, ushort* __restrict__ Wt,
    int K, int Nout, int rows)
{
    int idx = blockIdx.x * 256 + threadIdx.x;
    if (idx >= rows * K) return;
    int r = idx / K;
    int c = idx - r * K;
    float v = (r < Nout) ? W[(size_t)c * Nout + r] : 0.f;
    Wt[idx] = f2bf(v);
}

// ---------------------------------------------------------------------------
// bf16 MFMA dense v2: C[M,Ncols] = act(A[M,K] @ Wt^T + bias)
// 4 waves/block; each wave: MR row-frags (16 rows each) x NT col-frags.
// Per K-step: NT B-loads + MR A-loads feed MR*NT MFMAs (4x the MFMA:load
// ratio of v1 at MR=4 — attacks the vmcnt-wait latency bound).
// cols covered per block: NT*16 starting at blockIdx.y*NT*16.
// Fragment map (R5-verified): a: row=rbase+fr, k=k0+fq*8; b: col=cb+n*16+fr;
// D: row=rbase+fq*4+j, col=cb+n*16+fr.
// ---------------------------------------------------------------------------
template <bool RELU, int MR, int NT, bool OUTF32, bool BIAS>
__global__ __launch_bounds__(256) void dense_mfma2_kernel(
    const ushort* __restrict__ A, const ushort* __restrict__ Wt,
    const float* __restrict__ bias, void* __restrict__ Cout,
    int M, int K, int Ncols)
{
    const int lane = threadIdx.x & 63;
    const int wave = threadIdx.x >> 6;
    const int fr   = lane & 15;
    const int fq   = lane >> 4;
    const int cb   = blockIdx.y * (NT * 16);          // col base this block

    const int rowblk = blockIdx.x * (4 * MR * 16) + wave * (MR * 16);

    // per-row A pointers (clamped for OOB tail reads)
    const ushort* Arow[MR];
    #pragma unroll
    for (int mr = 0; mr < MR; ++mr) {
        int r = rowblk + mr * 16 + fr;
        if (r >= M) r = M - 1;
        Arow[mr] = A + (size_t)r * K;
    }
    // per-col B pointers
    const ushort* Brow[NT];
    #pragma unroll
    for (int n = 0; n < NT; ++n)
        Brow[n] = Wt + (size_t)(cb + n * 16 + fr) * K;

    f32x4 acc[MR][NT];
    #pragma unroll
    for (int mr = 0; mr < MR; ++mr)
        #pragma unroll
        for (int n = 0; n < NT; ++n)
            acc[mr][n] = (f32x4){0.f, 0.f, 0.f, 0.f};

    const int ksteps = K >> 5;
    for (int ks = 0; ks < ksteps; ++ks) {
        const int k0 = ks * 32 + fq * 8;
        short8v b[NT];
        #pragma unroll
        for (int n = 0; n < NT; ++n) b[n] = *(const short8v*)(Brow[n] + k0);
        short8v a[MR];
        #pragma unroll
        for (int mr = 0; mr < MR; ++mr) a[mr] = *(const short8v*)(Arow[mr] + k0);
        #pragma unroll
        for (int mr = 0; mr < MR; ++mr)
            #pragma unroll
            for (int n = 0; n < NT; ++n)
                acc[mr][n] = __builtin_amdgcn_mfma_f32_16x16x32_bf16(a[mr], b[n], acc[mr][n], 0, 0, 0);
    }

    // epilogue
    float bv[NT];
    #pragma unroll
    for (int n = 0; n < NT; ++n) {
        int col = cb + n * 16 + fr;
        bv[n] = (BIAS && col < Ncols) ? bias[col] : 0.f;
    }
    #pragma unroll
    for (int mr = 0; mr < MR; ++mr) {
        const int rbase = rowblk + mr * 16 + fq * 4;
        #pragma unroll
        for (int n = 0; n < NT; ++n) {
            int col = cb + n * 16 + fr;
            if (col >= Ncols) continue;                  // dec2: 40 of 48
            #pragma unroll
            for (int j = 0; j < 4; ++j) {
                int r = rbase + j;
                if (r >= M) continue;
                float v = acc[mr][n][j] + bv[n];
                if (RELU) v = fmaxf(v, 0.f);
                if (OUTF32) ((float*)Cout)[(size_t)r * Ncols + col] = v;
                else        ((ushort*)Cout)[(size_t)r * Ncols + col] = f2bf(v);
            }
        }
    }
}

// ---------------------------------------------------------------------------
// CSR build: histogram -> exclusive scan -> fill   (R4-verified)
// ---------------------------------------------------------------------------
__global__ __launch_bounds__(256) void degree_kernel(
    const int* __restrict__ dst, int* __restrict__ cnt, int E)
{
    int e = blockIdx.x * 256 + threadIdx.x;
    if (e < E) atomicAdd(&cnt[dst[e]], 1);
}

__global__ __launch_bounds__(256) void scan_block_kernel(
    const int* __restrict__ cnt, int* __restrict__ rs,
    int* __restrict__ partials, int N)
{
    __shared__ int sm[256];
    int i = blockIdx.x * 256 + threadIdx.x;
    int v = (i < N) ? cnt[i] : 0;
    sm[threadIdx.x] = v;
    __syncthreads();
    #pragma unroll
    for (int off = 1; off < 256; off <<= 1) {
        int t = (threadIdx.x >= off) ? sm[threadIdx.x - off] : 0;
        __syncthreads();
        sm[threadIdx.x] += t;
        __syncthreads();
    }
    if (i < N) rs[i] = sm[threadIdx.x] - v;
    if (threadIdx.x == 255) partials[blockIdx.x] = sm[255];
}

__global__ __launch_bounds__(512) void scan_partials_kernel(
    int* __restrict__ partials, int nblk)
{
    __shared__ int sm[512];
    int v = (threadIdx.x < nblk) ? partials[threadIdx.x] : 0;
    sm[threadIdx.x] = v;
    __syncthreads();
    #pragma unroll
    for (int off = 1; off < 512; off <<= 1) {
        int t = (threadIdx.x >= off) ? sm[threadIdx.x - off] : 0;
        __syncthreads();
        sm[threadIdx.x] += t;
        __syncthreads();
    }
    if (threadIdx.x < nblk) partials[threadIdx.x] = sm[threadIdx.x] - v;
}

__global__ __launch_bounds__(256) void add_offsets_kernel(
    int* __restrict__ rs, const int* __restrict__ partials, int N, int E)
{
    int i = blockIdx.x * 256 + threadIdx.x;
    if (i < N) rs[i] += partials[blockIdx.x];
    if (i == N) rs[N] = E;
}

__global__ __launch_bounds__(256) void fill_kernel(
    const int* __restrict__ src, const int* __restrict__ dst,
    const int* __restrict__ rs, int* __restrict__ cursor,
    int* __restrict__ csr_src, int E)
{
    int e = blockIdx.x * 256 + threadIdx.x;
    if (e >= E) return;
    int d = dst[e];
    int pos = rs[d] + atomicAdd(&cursor[d], 1);
    csr_src[pos] = src[e];
}

// ---------------------------------------------------------------------------
// hout[n] = relu( sum_{e in in(n)} hw[csr_src[e]] + bias )   bf16 I/O, f32 acc
// ---------------------------------------------------------------------------
__global__ __launch_bounds__(256) void gather_agg_kernel(
    const ushort* __restrict__ hw, const int* __restrict__ csr_src,
    const int* __restrict__ rs, const float* __restrict__ bias,
    ushort* __restrict__ hout, int N)
{
    int node = (blockIdx.x * 256 + threadIdx.x) >> 6;
    if (node >= N) return;
    int lane = threadIdx.x & 63;
    int beg = rs[node];
    int end = rs[node + 1];
    float ax = 0.f, ay = 0.f;
    for (int i = beg; i < end; ++i) {
        int s = csr_src[i];
        uint v = *(const uint*)(hw + (size_t)s * 128 + lane * 2);
        ax += bflo(v);
        ay += bfhi(v);
    }
    float2 b = *(const float2*)(bias + lane * 2);
    ax = fmaxf(ax + b.x, 0.f);
    ay = fmaxf(ay + b.y, 0.f);
    uint o = (uint)f2bf(ax) | ((uint)f2bf(ay) << 16);
    *(uint*)(hout + (size_t)node * 128 + lane * 2) = o;
}

// ---------------------------------------------------------------------------
// out = log_softmax(logits f32) over 40 cols, one wave per row
// ---------------------------------------------------------------------------
__global__ __launch_bounds__(256) void log_softmax_kernel(
    const float* __restrict__ logits, float* __restrict__ out, int M)
{
    int w    = (int)(((long long)blockIdx.x * 256 + threadIdx.x) >> 6);
    int lane = threadIdx.x & 63;
    if (w >= M) return;
    float v = -3.402823466e38f;
    if (lane < 40) v = logits[(size_t)w * 40 + lane];
    float m = v;
    #pragma unroll
    for (int off = 32; off > 0; off >>= 1) m = fmaxf(m, __shfl_xor(m, off, 64));
    float e = (lane < 40) ? expf(v - m) : 0.f;
    float s = e;
    #pragma unroll
    for (int off = 32; off > 0; off >>= 1) s += __shfl_xor(s, off, 64);
    float ls = logf(s);
    if (lane < 40) out[(size_t)w * 40 + lane] = v - m - ls;
}

// ---------------------------------------------------------------------------
extern "C" void kernel_launch(void* const* d_in, const int* in_sizes, int n_in,
                              void* d_out, int out_size, void* d_ws, size_t ws_size,
                              hipStream_t stream)
{
    const float* x      = (const float*)d_in[0];
    const int*   edge   = (const int*)d_in[1];
    const float* enc_w1 = (const float*)d_in[2];
    const float* enc_b1 = (const float*)d_in[3];
    const float* enc_w2 = (const float*)d_in[4];
    const float* enc_b2 = (const float*)d_in[5];
    const float* gcn_w  = (const float*)d_in[6];
    const float* gcn_b  = (const float*)d_in[7];
    const float* dec_w1 = (const float*)d_in[8];
    const float* dec_b1 = (const float*)d_in[9];
    const float* dec_w2 = (const float*)d_in[10];
    const float* dec_b2 = (const float*)d_in[11];

    const int F_IN = 128, H_ENC = 256, D = 128, N_CLS = 40, R = 3;
    const int N = in_sizes[0] / F_IN;   // 100000
    const int E = in_sizes[1] / 2;      // 600000
    const int* src = edge;
    const int* dst = edge + E;

    // ---- workspace layout (bytes) ----
    char* p = (char*)d_ws;
    ushort* xb     = (ushort*)p;                 p += (size_t)N * 128 * 2;
    ushort* h1     = (ushort*)p;                 p += (size_t)N * 256 * 2;
    ushort* h      = (ushort*)p;                 p += (size_t)N * 128 * 2;
    ushort* hw     = (ushort*)p;                 p += (size_t)N * 128 * 2;
    float*  logits = (float*)p;                  p += (size_t)N * 40 * 4;
    ushort* enc1t  = (ushort*)p;                 p += 256 * 128 * 2;
    ushort* enc2t  = (ushort*)p;                 p += 128 * 256 * 2;
    ushort* gcnt   = (ushort*)p;                 p += 3 * 128 * 128 * 2;
    ushort* dec1t  = (ushort*)p;                 p += 128 * 128 * 2;
    ushort* dec2t  = (ushort*)p;                 p += 48 * 128 * 2;
    int* csr_src   = (int*)p;
    int* rs        = csr_src + E;
    int* cnt       = rs + (N + 1);
    int* partials  = cnt + N;

    float* out = (float*)d_out;
    dim3 blk(256);

    // ---- one-time converts ----
    cast_bf16_kernel<<<(N * 128 / 4 + 255) / 256, blk, 0, stream>>>(x, xb, N * 128 / 4);
    wtrans_kernel<<<(256 * 128 + 255) / 256, blk, 0, stream>>>(enc_w1, enc1t, 128, 256, 256);
    wtrans_kernel<<<(128 * 256 + 255) / 256, blk, 0, stream>>>(enc_w2, enc2t, 256, 128, 128);
    for (int r = 0; r < R; ++r)
        wtrans_kernel<<<(128 * 128 + 255) / 256, blk, 0, stream>>>(
            gcn_w + (size_t)r * 128 * 128, gcnt + (size_t)r * 128 * 128, 128, 128, 128);
    wtrans_kernel<<<(128 * 128 + 255) / 256, blk, 0, stream>>>(dec_w1, dec1t, 128, 128, 128);
    wtrans_kernel<<<(48 * 128 + 255) / 256, blk, 0, stream>>>(dec_w2, dec2t, 128, 40, 48);

    // ---- CSR build ----
    const int nblkN = (N + 255) / 256;
    const int nblkE = (E + 255) / 256;
    hipMemsetAsync(cnt, 0, (size_t)N * sizeof(int), stream);
    degree_kernel<<<nblkE, blk, 0, stream>>>(dst, cnt, E);
    scan_block_kernel<<<nblkN, blk, 0, stream>>>(cnt, rs, partials, N);
    scan_partials_kernel<<<1, 512, 0, stream>>>(partials, nblkN);
    add_offsets_kernel<<<nblkN + 1, blk, 0, stream>>>(rs, partials, N, E);
    hipMemsetAsync(cnt, 0, (size_t)N * sizeof(int), stream);
    fill_kernel<<<nblkE, blk, 0, stream>>>(src, dst, rs, cnt, csr_src, E);

    // ---- dense grid: 4 waves x MR(4)*16 rows = 256 rows/block ----
    const int gmx = (N + 255) / 256;   // 391

    // encoder
    dense_mfma2_kernel<true, 4, 8, false, true><<<dim3(gmx, 2), blk, 0, stream>>>(
        xb, enc1t, enc_b1, h1, N, 128, 256);
    dense_mfma2_kernel<false, 4, 8, false, true><<<dim3(gmx, 1), blk, 0, stream>>>(
        h1, enc2t, enc_b2, h, N, 256, 128);

    // 3-hop GCN
    const int aggb = (N * 64 + 255) / 256;
    for (int r = 0; r < R; ++r) {
        dense_mfma2_kernel<false, 4, 8, false, false><<<dim3(gmx, 1), blk, 0, stream>>>(
            h, gcnt + (size_t)r * 128 * 128, nullptr, hw, N, 128, 128);
        gather_agg_kernel<<<aggb, blk, 0, stream>>>(
            hw, csr_src, rs, gcn_b + (size_t)r * 128, h, N);
    }

    // decoder
    dense_mfma2_kernel<true, 4, 8, false, true><<<dim3(gmx, 1), blk, 0, stream>>>(
        h, dec1t, dec_b1, hw /*h2*/, N, 128, 128);
    dense_mfma2_kernel<false, 4, 3, true, true><<<dim3(gmx, 1), blk, 0, stream>>>(
        hw, dec2t, dec_b2, logits, N, 128, 40);

    const int smb = (N + 3) / 4;
    log_softmax_kernel<<<smb, blk, 0, stream>>>(logits, out, N);
}

// Round 7
// 582.264 us; speedup vs baseline: 1.2629x; 1.2629x over previous
//
#include <hip/hip_runtime.h>
#include <hip/hip_bf16.h>
#include <cstddef>

typedef __attribute__((ext_vector_type(8))) short short8v;   // 8 x bf16 = 4 VGPR
typedef __attribute__((ext_vector_type(4))) float f32x4;     // MFMA accumulator

__device__ inline ushort f2bf(float f) {                     // f32 -> bf16 RNE
    uint u = __float_as_uint(f);
    uint r = (u + 0x7fffu + ((u >> 16) & 1u)) >> 16;
    return (ushort)r;
}
__device__ inline float bflo(uint v) { return __uint_as_float(v << 16); }
__device__ inline float bfhi(uint v) { return __uint_as_float(v & 0xffff0000u); }

// ---------------------------------------------------------------------------
// cast f32 -> bf16, 4 elements/thread
// ---------------------------------------------------------------------------
__global__ __launch_bounds__(256) void cast_bf16_kernel(
    const float* __restrict__ in, ushort* __restrict__ out, int n4)
{
    int i = blockIdx.x * 256 + threadIdx.x;
    if (i >= n4) return;
    float4 v = ((const float4*)in)[i];
    ushort4 o = { f2bf(v.x), f2bf(v.y), f2bf(v.z), f2bf(v.w) };
    ((ushort4*)out)[i] = o;
}

// ---------------------------------------------------------------------------
// W[K][Nout] f32  ->  Wt[rows][K] bf16  (rows >= Nout, zero-padded)
// ---------------------------------------------------------------------------
__global__ __launch_bounds__(256) void wtrans_kernel(
    const float* __restrict__ W, ushort* __restrict__ Wt,
    int K, int Nout, int rows)
{
    int idx = blockIdx.x * 256 + threadIdx.x;
    if (idx >= rows * K) return;
    int r = idx / K;
    int c = idx - r * K;
    float v = (r < Nout) ? W[(size_t)c * Nout + r] : 0.f;
    Wt[idx] = f2bf(v);
}

// ---------------------------------------------------------------------------
// bf16 MFMA dense v3: C[M,Ncols] = act(A[M,K] @ Wt^T + bias)
// - Weight tile (NT*16 rows x KT) staged in LDS once per block, XOR-swizzled
//   (byte ^= (row&7)<<4) to kill the 16-way fr-stride bank conflict (G4).
// - All A-frags hoisted to registers before the MFMA loop (latency paid once).
// - 4 waves/block, MR*16 rows/wave -> block covers 4*MR*16 rows.
// Fragment map (R5-verified): a: row=rowblk+mr*16+fr, k=k0+fq*8;
// b: col=cb+n*16+fr; D: row=rowblk+mr*16+fq*4+j, col=cb+n*16+fr.
// ---------------------------------------------------------------------------
template <bool RELU, int MR, int NT, int KT, bool OUTF32, bool BIAS>
__global__ __launch_bounds__(256) void dense_mfma3_kernel(
    const ushort* __restrict__ A, const ushort* __restrict__ Wt,
    const float* __restrict__ bias, void* __restrict__ Cout,
    int M, int Ncols)
{
    constexpr int KSTEPS = KT / 32;
    constexpr int ROWS_B = NT * 16;
    constexpr int ROW_BYTES = KT * 2;
    constexpr int CHUNKS_PER_ROW = ROW_BYTES / 16;   // 16B chunks per row

    __shared__ __align__(16) char lds[ROWS_B * ROW_BYTES];

    const int tid  = threadIdx.x;
    const int lane = tid & 63;
    const int wave = tid >> 6;
    const int fr   = lane & 15;
    const int fq   = lane >> 4;
    const int cb   = blockIdx.y * ROWS_B;            // weight-row (=col) base

    // ---- stage weight tile into LDS with XOR swizzle ----
    {
        constexpr int TOTAL = ROWS_B * CHUNKS_PER_ROW;
        #pragma unroll
        for (int c0 = 0; c0 < TOTAL; c0 += 256) {
            int c = c0 + tid;
            if (TOTAL % 256 != 0 && c >= TOTAL) break;
            int r = c / CHUNKS_PER_ROW;
            int w = c - r * CHUNKS_PER_ROW;
            short8v v = *(const short8v*)(Wt + (size_t)(cb + r) * KT + w * 8);
            int dstByte = r * ROW_BYTES + ((w * 16) ^ ((r & 7) << 4));
            *(short8v*)(lds + dstByte) = v;
        }
    }
    __syncthreads();

    const int rowblk = blockIdx.x * (4 * MR * 16) + wave * (MR * 16);

    // ---- hoist all A fragments (streaming HBM read, paid once) ----
    short8v aReg[MR * KSTEPS];
    #pragma unroll
    for (int ks = 0; ks < KSTEPS; ++ks)
        #pragma unroll
        for (int mr = 0; mr < MR; ++mr) {
            int r = rowblk + mr * 16 + fr;
            if (r >= M) r = M - 1;
            aReg[ks * MR + mr] = *(const short8v*)(A + (size_t)r * KT + ks * 32 + fq * 8);
        }

    f32x4 acc[MR][NT];
    #pragma unroll
    for (int mr = 0; mr < MR; ++mr)
        #pragma unroll
        for (int n = 0; n < NT; ++n)
            acc[mr][n] = (f32x4){0.f, 0.f, 0.f, 0.f};

    // ---- MFMA loop: B from LDS, A from registers ----
    #pragma unroll
    for (int ks = 0; ks < KSTEPS; ++ks) {
        const int kByte = ks * 64 + fq * 16;
        short8v b[NT];
        #pragma unroll
        for (int n = 0; n < NT; ++n) {
            int lr = n * 16 + fr;
            b[n] = *(const short8v*)(lds + lr * ROW_BYTES + (kByte ^ ((lr & 7) << 4)));
        }
        #pragma unroll
        for (int mr = 0; mr < MR; ++mr)
            #pragma unroll
            for (int n = 0; n < NT; ++n)
                acc[mr][n] = __builtin_amdgcn_mfma_f32_16x16x32_bf16(
                    aReg[ks * MR + mr], b[n], acc[mr][n], 0, 0, 0);
    }

    // ---- epilogue ----
    float bv[NT];
    #pragma unroll
    for (int n = 0; n < NT; ++n) {
        int col = cb + n * 16 + fr;
        bv[n] = (BIAS && col < Ncols) ? bias[col] : 0.f;
    }
    #pragma unroll
    for (int mr = 0; mr < MR; ++mr) {
        const int rbase = rowblk + mr * 16 + fq * 4;
        #pragma unroll
        for (int n = 0; n < NT; ++n) {
            int col = cb + n * 16 + fr;
            if (col >= Ncols) continue;                  // dec2: 40 of 48
            #pragma unroll
            for (int j = 0; j < 4; ++j) {
                int r = rbase + j;
                if (r >= M) continue;
                float v = acc[mr][n][j] + bv[n];
                if (RELU) v = fmaxf(v, 0.f);
                if (OUTF32) ((float*)Cout)[(size_t)r * Ncols + col] = v;
                else        ((ushort*)Cout)[(size_t)r * Ncols + col] = f2bf(v);
            }
        }
    }
}

// ---------------------------------------------------------------------------
// CSR build: histogram -> exclusive scan -> fill   (R4-verified)
// ---------------------------------------------------------------------------
__global__ __launch_bounds__(256) void degree_kernel(
    const int* __restrict__ dst, int* __restrict__ cnt, int E)
{
    int e = blockIdx.x * 256 + threadIdx.x;
    if (e < E) atomicAdd(&cnt[dst[e]], 1);
}

__global__ __launch_bounds__(256) void scan_block_kernel(
    const int* __restrict__ cnt, int* __restrict__ rs,
    int* __restrict__ partials, int N)
{
    __shared__ int sm[256];
    int i = blockIdx.x * 256 + threadIdx.x;
    int v = (i < N) ? cnt[i] : 0;
    sm[threadIdx.x] = v;
    __syncthreads();
    #pragma unroll
    for (int off = 1; off < 256; off <<= 1) {
        int t = (threadIdx.x >= off) ? sm[threadIdx.x - off] : 0;
        __syncthreads();
        sm[threadIdx.x] += t;
        __syncthreads();
    }
    if (i < N) rs[i] = sm[threadIdx.x] - v;
    if (threadIdx.x == 255) partials[blockIdx.x] = sm[255];
}

__global__ __launch_bounds__(512) void scan_partials_kernel(
    int* __restrict__ partials, int nblk)
{
    __shared__ int sm[512];
    int v = (threadIdx.x < nblk) ? partials[threadIdx.x] : 0;
    sm[threadIdx.x] = v;
    __syncthreads();
    #pragma unroll
    for (int off = 1; off < 512; off <<= 1) {
        int t = (threadIdx.x >= off) ? sm[threadIdx.x - off] : 0;
        __syncthreads();
        sm[threadIdx.x] += t;
        __syncthreads();
    }
    if (threadIdx.x < nblk) partials[threadIdx.x] = sm[threadIdx.x] - v;
}

__global__ __launch_bounds__(256) void add_offsets_kernel(
    int* __restrict__ rs, const int* __restrict__ partials, int N, int E)
{
    int i = blockIdx.x * 256 + threadIdx.x;
    if (i < N) rs[i] += partials[blockIdx.x];
    if (i == N) rs[N] = E;
}

__global__ __launch_bounds__(256) void fill_kernel(
    const int* __restrict__ src, const int* __restrict__ dst,
    const int* __restrict__ rs, int* __restrict__ cursor,
    int* __restrict__ csr_src, int E)
{
    int e = blockIdx.x * 256 + threadIdx.x;
    if (e >= E) return;
    int d = dst[e];
    int pos = rs[d] + atomicAdd(&cursor[d], 1);
    csr_src[pos] = src[e];
}

// ---------------------------------------------------------------------------
// hout[n] = relu( sum_{e in in(n)} hw[csr_src[e]] + bias )   bf16 I/O, f32 acc
// ---------------------------------------------------------------------------
__global__ __launch_bounds__(256) void gather_agg_kernel(
    const ushort* __restrict__ hw, const int* __restrict__ csr_src,
    const int* __restrict__ rs, const float* __restrict__ bias,
    ushort* __restrict__ hout, int N)
{
    int node = (blockIdx.x * 256 + threadIdx.x) >> 6;
    if (node >= N) return;
    int lane = threadIdx.x & 63;
    int beg = rs[node];
    int end = rs[node + 1];
    float ax = 0.f, ay = 0.f;
    for (int i = beg; i < end; ++i) {
        int s = csr_src[i];
        uint v = *(const uint*)(hw + (size_t)s * 128 + lane * 2);
        ax += bflo(v);
        ay += bfhi(v);
    }
    float2 b = *(const float2*)(bias + lane * 2);
    ax = fmaxf(ax + b.x, 0.f);
    ay = fmaxf(ay + b.y, 0.f);
    uint o = (uint)f2bf(ax) | ((uint)f2bf(ay) << 16);
    *(uint*)(hout + (size_t)node * 128 + lane * 2) = o;
}

// ---------------------------------------------------------------------------
// out = log_softmax(logits f32) over 40 cols, one wave per row
// ---------------------------------------------------------------------------
__global__ __launch_bounds__(256) void log_softmax_kernel(
    const float* __restrict__ logits, float* __restrict__ out, int M)
{
    int w    = (int)(((long long)blockIdx.x * 256 + threadIdx.x) >> 6);
    int lane = threadIdx.x & 63;
    if (w >= M) return;
    float v = -3.402823466e38f;
    if (lane < 40) v = logits[(size_t)w * 40 + lane];
    float m = v;
    #pragma unroll
    for (int off = 32; off > 0; off >>= 1) m = fmaxf(m, __shfl_xor(m, off, 64));
    float e = (lane < 40) ? expf(v - m) : 0.f;
    float s = e;
    #pragma unroll
    for (int off = 32; off > 0; off >>= 1) s += __shfl_xor(s, off, 64);
    float ls = logf(s);
    if (lane < 40) out[(size_t)w * 40 + lane] = v - m - ls;
}

// ---------------------------------------------------------------------------
extern "C" void kernel_launch(void* const* d_in, const int* in_sizes, int n_in,
                              void* d_out, int out_size, void* d_ws, size_t ws_size,
                              hipStream_t stream)
{
    const float* x      = (const float*)d_in[0];
    const int*   edge   = (const int*)d_in[1];
    const float* enc_w1 = (const float*)d_in[2];
    const float* enc_b1 = (const float*)d_in[3];
    const float* enc_w2 = (const float*)d_in[4];
    const float* enc_b2 = (const float*)d_in[5];
    const float* gcn_w  = (const float*)d_in[6];
    const float* gcn_b  = (const float*)d_in[7];
    const float* dec_w1 = (const float*)d_in[8];
    const float* dec_b1 = (const float*)d_in[9];
    const float* dec_w2 = (const float*)d_in[10];
    const float* dec_b2 = (const float*)d_in[11];

    const int F_IN = 128, H_ENC = 256, D = 128, N_CLS = 40, R = 3;
    const int N = in_sizes[0] / F_IN;   // 100000
    const int E = in_sizes[1] / 2;      // 600000
    const int* src = edge;
    const int* dst = edge + E;

    // ---- workspace layout (bytes) ----
    char* p = (char*)d_ws;
    ushort* xb     = (ushort*)p;                 p += (size_t)N * 128 * 2;
    ushort* h1     = (ushort*)p;                 p += (size_t)N * 256 * 2;
    ushort* h      = (ushort*)p;                 p += (size_t)N * 128 * 2;
    ushort* hw     = (ushort*)p;                 p += (size_t)N * 128 * 2;
    float*  logits = (float*)p;                  p += (size_t)N * 40 * 4;
    ushort* enc1t  = (ushort*)p;                 p += 256 * 128 * 2;
    ushort* enc2t  = (ushort*)p;                 p += 128 * 256 * 2;
    ushort* gcnt   = (ushort*)p;                 p += 3 * 128 * 128 * 2;
    ushort* dec1t  = (ushort*)p;                 p += 128 * 128 * 2;
    ushort* dec2t  = (ushort*)p;                 p += 48 * 128 * 2;
    int* csr_src   = (int*)p;
    int* rs        = csr_src + E;
    int* cnt       = rs + (N + 1);
    int* partials  = cnt + N;

    float* out = (float*)d_out;
    dim3 blk(256);

    // ---- one-time converts ----
    cast_bf16_kernel<<<(N * 128 / 4 + 255) / 256, blk, 0, stream>>>(x, xb, N * 128 / 4);
    wtrans_kernel<<<(256 * 128 + 255) / 256, blk, 0, stream>>>(enc_w1, enc1t, 128, 256, 256);
    wtrans_kernel<<<(128 * 256 + 255) / 256, blk, 0, stream>>>(enc_w2, enc2t, 256, 128, 128);
    for (int r = 0; r < R; ++r)
        wtrans_kernel<<<(128 * 128 + 255) / 256, blk, 0, stream>>>(
            gcn_w + (size_t)r * 128 * 128, gcnt + (size_t)r * 128 * 128, 128, 128, 128);
    wtrans_kernel<<<(128 * 128 + 255) / 256, blk, 0, stream>>>(dec_w1, dec1t, 128, 128, 128);
    wtrans_kernel<<<(48 * 128 + 255) / 256, blk, 0, stream>>>(dec_w2, dec2t, 128, 40, 48);

    // ---- CSR build ----
    const int nblkN = (N + 255) / 256;
    const int nblkE = (E + 255) / 256;
    hipMemsetAsync(cnt, 0, (size_t)N * sizeof(int), stream);
    degree_kernel<<<nblkE, blk, 0, stream>>>(dst, cnt, E);
    scan_block_kernel<<<nblkN, blk, 0, stream>>>(cnt, rs, partials, N);
    scan_partials_kernel<<<1, 512, 0, stream>>>(partials, nblkN);
    add_offsets_kernel<<<nblkN + 1, blk, 0, stream>>>(rs, partials, N, E);
    hipMemsetAsync(cnt, 0, (size_t)N * sizeof(int), stream);
    fill_kernel<<<nblkE, blk, 0, stream>>>(src, dst, rs, cnt, csr_src, E);

    // ---- dense grid: 4 waves x MR(2)*16 rows = 128 rows/block ----
    const int gdx = (N + 127) / 128;   // 782

    // encoder: enc1 cols 256 via y=2 (NT=8); enc2 K=256 via NT=4, y=2
    dense_mfma3_kernel<true, 2, 8, 128, false, true><<<dim3(gdx, 2), blk, 0, stream>>>(
        xb, enc1t, enc_b1, h1, N, 256);
    dense_mfma3_kernel<false, 2, 4, 256, false, true><<<dim3(gdx, 2), blk, 0, stream>>>(
        h1, enc2t, enc_b2, h, N, 128);

    // 3-hop GCN
    const int aggb = (N * 64 + 255) / 256;
    for (int r = 0; r < R; ++r) {
        dense_mfma3_kernel<false, 2, 8, 128, false, false><<<dim3(gdx, 1), blk, 0, stream>>>(
            h, gcnt + (size_t)r * 128 * 128, nullptr, hw, N, 128);
        gather_agg_kernel<<<aggb, blk, 0, stream>>>(
            hw, csr_src, rs, gcn_b + (size_t)r * 128, h, N);
    }

    // decoder
    dense_mfma3_kernel<true, 2, 8, 128, false, true><<<dim3(gdx, 1), blk, 0, stream>>>(
        h, dec1t, dec_b1, hw /*h2*/, N, 128);
    dense_mfma3_kernel<false, 2, 3, 128, true, true><<<dim3(gdx, 1), blk, 0, stream>>>(
        hw, dec2t, dec_b2, logits, N, 40);

    const int smb = (N + 3) / 4;
    log_softmax_kernel<<<smb, blk, 0, stream>>>(logits, out, N);
}

// Round 8
// 492.892 us; speedup vs baseline: 1.4919x; 1.1813x over previous
//
#include <hip/hip_runtime.h>
#include <hip/hip_bf16.h>
#include <cstddef>

typedef __attribute__((ext_vector_type(8))) short short8v;   // 8 x bf16 = 4 VGPR
typedef __attribute__((ext_vector_type(4))) float f32x4;     // MFMA accumulator

__device__ inline ushort f2bf(float f) {                     // f32 -> bf16 RNE
    uint u = __float_as_uint(f);
    uint r = (u + 0x7fffu + ((u >> 16) & 1u)) >> 16;
    return (ushort)r;
}
__device__ inline float bflo(uint v) { return __uint_as_float(v << 16); }
__device__ inline float bfhi(uint v) { return __uint_as_float(v & 0xffff0000u); }

// ---------------------------------------------------------------------------
// cast f32 -> bf16, 4 elements/thread
// ---------------------------------------------------------------------------
__global__ __launch_bounds__(256) void cast_bf16_kernel(
    const float* __restrict__ in, ushort* __restrict__ out, int n4)
{
    int i = blockIdx.x * 256 + threadIdx.x;
    if (i >= n4) return;
    float4 v = ((const float4*)in)[i];
    ushort4 o = { f2bf(v.x), f2bf(v.y), f2bf(v.z), f2bf(v.w) };
    ((ushort4*)out)[i] = o;
}

// ---------------------------------------------------------------------------
// W[K][Nout] f32  ->  Wt[rows][K] bf16  (rows >= Nout, zero-padded)
// ---------------------------------------------------------------------------
__global__ __launch_bounds__(256) void wtrans_kernel(
    const float* __restrict__ W, ushort* __restrict__ Wt,
    int K, int Nout, int rows)
{
    int idx = blockIdx.x * 256 + threadIdx.x;
    if (idx >= rows * K) return;
    int r = idx / K;
    int c = idx - r * K;
    float v = (r < Nout) ? W[(size_t)c * Nout + r] : 0.f;
    Wt[idx] = f2bf(v);
}

// ---------------------------------------------------------------------------
// bf16 MFMA dense v3: C[M,Ncols] = act(A[M,K] @ Wt^T + bias)
// LDS-staged swizzled weight tile + hoisted A-frags (R7-verified).
// ---------------------------------------------------------------------------
template <bool RELU, int MR, int NT, int KT, bool OUTF32, bool BIAS>
__global__ __launch_bounds__(256) void dense_mfma3_kernel(
    const ushort* __restrict__ A, const ushort* __restrict__ Wt,
    const float* __restrict__ bias, void* __restrict__ Cout,
    int M, int Ncols)
{
    constexpr int KSTEPS = KT / 32;
    constexpr int ROWS_B = NT * 16;
    constexpr int ROW_BYTES = KT * 2;
    constexpr int CHUNKS_PER_ROW = ROW_BYTES / 16;   // 16B chunks per row

    __shared__ __align__(16) char lds[ROWS_B * ROW_BYTES];

    const int tid  = threadIdx.x;
    const int lane = tid & 63;
    const int wave = tid >> 6;
    const int fr   = lane & 15;
    const int fq   = lane >> 4;
    const int cb   = blockIdx.y * ROWS_B;            // weight-row (=col) base

    // ---- stage weight tile into LDS with XOR swizzle ----
    {
        constexpr int TOTAL = ROWS_B * CHUNKS_PER_ROW;
        #pragma unroll
        for (int c0 = 0; c0 < TOTAL; c0 += 256) {
            int c = c0 + tid;
            if (TOTAL % 256 != 0 && c >= TOTAL) break;
            int r = c / CHUNKS_PER_ROW;
            int w = c - r * CHUNKS_PER_ROW;
            short8v v = *(const short8v*)(Wt + (size_t)(cb + r) * KT + w * 8);
            int dstByte = r * ROW_BYTES + ((w * 16) ^ ((r & 7) << 4));
            *(short8v*)(lds + dstByte) = v;
        }
    }
    __syncthreads();

    const int rowblk = blockIdx.x * (4 * MR * 16) + wave * (MR * 16);

    // ---- hoist all A fragments (streaming HBM read, paid once) ----
    short8v aReg[MR * KSTEPS];
    #pragma unroll
    for (int ks = 0; ks < KSTEPS; ++ks)
        #pragma unroll
        for (int mr = 0; mr < MR; ++mr) {
            int r = rowblk + mr * 16 + fr;
            if (r >= M) r = M - 1;
            aReg[ks * MR + mr] = *(const short8v*)(A + (size_t)r * KT + ks * 32 + fq * 8);
        }

    f32x4 acc[MR][NT];
    #pragma unroll
    for (int mr = 0; mr < MR; ++mr)
        #pragma unroll
        for (int n = 0; n < NT; ++n)
            acc[mr][n] = (f32x4){0.f, 0.f, 0.f, 0.f};

    // ---- MFMA loop: B from LDS, A from registers ----
    #pragma unroll
    for (int ks = 0; ks < KSTEPS; ++ks) {
        const int kByte = ks * 64 + fq * 16;
        short8v b[NT];
        #pragma unroll
        for (int n = 0; n < NT; ++n) {
            int lr = n * 16 + fr;
            b[n] = *(const short8v*)(lds + lr * ROW_BYTES + (kByte ^ ((lr & 7) << 4)));
        }
        #pragma unroll
        for (int mr = 0; mr < MR; ++mr)
            #pragma unroll
            for (int n = 0; n < NT; ++n)
                acc[mr][n] = __builtin_amdgcn_mfma_f32_16x16x32_bf16(
                    aReg[ks * MR + mr], b[n], acc[mr][n], 0, 0, 0);
    }

    // ---- epilogue ----
    float bv[NT];
    #pragma unroll
    for (int n = 0; n < NT; ++n) {
        int col = cb + n * 16 + fr;
        bv[n] = (BIAS && col < Ncols) ? bias[col] : 0.f;
    }
    #pragma unroll
    for (int mr = 0; mr < MR; ++mr) {
        const int rbase = rowblk + mr * 16 + fq * 4;
        #pragma unroll
        for (int n = 0; n < NT; ++n) {
            int col = cb + n * 16 + fr;
            if (col >= Ncols) continue;                  // dec2: 40 of 48
            #pragma unroll
            for (int j = 0; j < 4; ++j) {
                int r = rbase + j;
                if (r >= M) continue;
                float v = acc[mr][n][j] + bv[n];
                if (RELU) v = fmaxf(v, 0.f);
                if (OUTF32) ((float*)Cout)[(size_t)r * Ncols + col] = v;
                else        ((ushort*)Cout)[(size_t)r * Ncols + col] = f2bf(v);
            }
        }
    }
}

// ---------------------------------------------------------------------------
// CSR build: histogram -> exclusive scan -> fill   (R4-verified)
// ---------------------------------------------------------------------------
__global__ __launch_bounds__(256) void degree_kernel(
    const int* __restrict__ dst, int* __restrict__ cnt, int E)
{
    int e = blockIdx.x * 256 + threadIdx.x;
    if (e < E) atomicAdd(&cnt[dst[e]], 1);
}

__global__ __launch_bounds__(256) void scan_block_kernel(
    const int* __restrict__ cnt, int* __restrict__ rs,
    int* __restrict__ partials, int N)
{
    __shared__ int sm[256];
    int i = blockIdx.x * 256 + threadIdx.x;
    int v = (i < N) ? cnt[i] : 0;
    sm[threadIdx.x] = v;
    __syncthreads();
    #pragma unroll
    for (int off = 1; off < 256; off <<= 1) {
        int t = (threadIdx.x >= off) ? sm[threadIdx.x - off] : 0;
        __syncthreads();
        sm[threadIdx.x] += t;
        __syncthreads();
    }
    if (i < N) rs[i] = sm[threadIdx.x] - v;
    if (threadIdx.x == 255) partials[blockIdx.x] = sm[255];
}

__global__ __launch_bounds__(512) void scan_partials_kernel(
    int* __restrict__ partials, int nblk)
{
    __shared__ int sm[512];
    int v = (threadIdx.x < nblk) ? partials[threadIdx.x] : 0;
    sm[threadIdx.x] = v;
    __syncthreads();
    #pragma unroll
    for (int off = 1; off < 512; off <<= 1) {
        int t = (threadIdx.x >= off) ? sm[threadIdx.x - off] : 0;
        __syncthreads();
        sm[threadIdx.x] += t;
        __syncthreads();
    }
    if (threadIdx.x < nblk) partials[threadIdx.x] = sm[threadIdx.x] - v;
}

__global__ __launch_bounds__(256) void add_offsets_kernel(
    int* __restrict__ rs, const int* __restrict__ partials, int N, int E)
{
    int i = blockIdx.x * 256 + threadIdx.x;
    if (i < N) rs[i] += partials[blockIdx.x];
    if (i == N) rs[N] = E;
}

__global__ __launch_bounds__(256) void fill_kernel(
    const int* __restrict__ src, const int* __restrict__ dst,
    const int* __restrict__ rs, int* __restrict__ cursor,
    int* __restrict__ csr_src, int E)
{
    int e = blockIdx.x * 256 + threadIdx.x;
    if (e >= E) return;
    int d = dst[e];
    int pos = rs[d] + atomicAdd(&cursor[d], 1);
    csr_src[pos] = src[e];
}

// ---------------------------------------------------------------------------
// hout[n] = relu( sum_{e in in(n)} hw[csr_src[e]] + bias )   bf16 I/O, f32 acc
// One wave/node. Edge loop unrolled 4-deep: 4 independent row-loads in
// flight per wave (vs 1) — attacks the dependent-load latency bound (R7).
// ---------------------------------------------------------------------------
__global__ __launch_bounds__(256) void gather_agg_kernel(
    const ushort* __restrict__ hw, const int* __restrict__ csr_src,
    const int* __restrict__ rs, const float* __restrict__ bias,
    ushort* __restrict__ hout, int N)
{
    int node = (blockIdx.x * 256 + threadIdx.x) >> 6;
    if (node >= N) return;
    int lane = threadIdx.x & 63;
    int beg = rs[node];
    int end = rs[node + 1];
    const size_t loff = (size_t)lane * 2;

    float ax = 0.f, ay = 0.f;
    int i = beg;
    for (; i + 4 <= end; i += 4) {
        int s0 = csr_src[i + 0];
        int s1 = csr_src[i + 1];
        int s2 = csr_src[i + 2];
        int s3 = csr_src[i + 3];
        uint v0 = *(const uint*)(hw + (size_t)s0 * 128 + loff);
        uint v1 = *(const uint*)(hw + (size_t)s1 * 128 + loff);
        uint v2 = *(const uint*)(hw + (size_t)s2 * 128 + loff);
        uint v3 = *(const uint*)(hw + (size_t)s3 * 128 + loff);
        ax += bflo(v0) + bflo(v1) + bflo(v2) + bflo(v3);
        ay += bfhi(v0) + bfhi(v1) + bfhi(v2) + bfhi(v3);
    }
    if (i + 2 <= end) {
        int s0 = csr_src[i + 0];
        int s1 = csr_src[i + 1];
        uint v0 = *(const uint*)(hw + (size_t)s0 * 128 + loff);
        uint v1 = *(const uint*)(hw + (size_t)s1 * 128 + loff);
        ax += bflo(v0) + bflo(v1);
        ay += bfhi(v0) + bfhi(v1);
        i += 2;
    }
    if (i < end) {
        int s0 = csr_src[i];
        uint v0 = *(const uint*)(hw + (size_t)s0 * 128 + loff);
        ax += bflo(v0);
        ay += bfhi(v0);
    }

    float2 b = *(const float2*)(bias + loff);
    ax = fmaxf(ax + b.x, 0.f);
    ay = fmaxf(ay + b.y, 0.f);
    uint o = (uint)f2bf(ax) | ((uint)f2bf(ay) << 16);
    *(uint*)(hout + (size_t)node * 128 + loff) = o;
}

// ---------------------------------------------------------------------------
// out = log_softmax(logits f32) over 40 cols, one wave per row
// ---------------------------------------------------------------------------
__global__ __launch_bounds__(256) void log_softmax_kernel(
    const float* __restrict__ logits, float* __restrict__ out, int M)
{
    int w    = (int)(((long long)blockIdx.x * 256 + threadIdx.x) >> 6);
    int lane = threadIdx.x & 63;
    if (w >= M) return;
    float v = -3.402823466e38f;
    if (lane < 40) v = logits[(size_t)w * 40 + lane];
    float m = v;
    #pragma unroll
    for (int off = 32; off > 0; off >>= 1) m = fmaxf(m, __shfl_xor(m, off, 64));
    float e = (lane < 40) ? expf(v - m) : 0.f;
    float s = e;
    #pragma unroll
    for (int off = 32; off > 0; off >>= 1) s += __shfl_xor(s, off, 64);
    float ls = logf(s);
    if (lane < 40) out[(size_t)w * 40 + lane] = v - m - ls;
}

// ---------------------------------------------------------------------------
extern "C" void kernel_launch(void* const* d_in, const int* in_sizes, int n_in,
                              void* d_out, int out_size, void* d_ws, size_t ws_size,
                              hipStream_t stream)
{
    const float* x      = (const float*)d_in[0];
    const int*   edge   = (const int*)d_in[1];
    const float* enc_w1 = (const float*)d_in[2];
    const float* enc_b1 = (const float*)d_in[3];
    const float* enc_w2 = (const float*)d_in[4];
    const float* enc_b2 = (const float*)d_in[5];
    const float* gcn_w  = (const float*)d_in[6];
    const float* gcn_b  = (const float*)d_in[7];
    const float* dec_w1 = (const float*)d_in[8];
    const float* dec_b1 = (const float*)d_in[9];
    const float* dec_w2 = (const float*)d_in[10];
    const float* dec_b2 = (const float*)d_in[11];

    const int F_IN = 128, H_ENC = 256, D = 128, N_CLS = 40, R = 3;
    const int N = in_sizes[0] / F_IN;   // 100000
    const int E = in_sizes[1] / 2;      // 600000
    const int* src = edge;
    const int* dst = edge + E;

    // ---- workspace layout (bytes) ----
    char* p = (char*)d_ws;
    ushort* xb     = (ushort*)p;                 p += (size_t)N * 128 * 2;
    ushort* h1     = (ushort*)p;                 p += (size_t)N * 256 * 2;
    ushort* h      = (ushort*)p;                 p += (size_t)N * 128 * 2;
    ushort* hw     = (ushort*)p;                 p += (size_t)N * 128 * 2;
    float*  logits = (float*)p;                  p += (size_t)N * 40 * 4;
    ushort* enc1t  = (ushort*)p;                 p += 256 * 128 * 2;
    ushort* enc2t  = (ushort*)p;                 p += 128 * 256 * 2;
    ushort* gcnt   = (ushort*)p;                 p += 3 * 128 * 128 * 2;
    ushort* dec1t  = (ushort*)p;                 p += 128 * 128 * 2;
    ushort* dec2t  = (ushort*)p;                 p += 48 * 128 * 2;
    int* csr_src   = (int*)p;
    int* rs        = csr_src + E;
    int* cnt       = rs + (N + 1);
    int* partials  = cnt + N;

    float* out = (float*)d_out;
    dim3 blk(256);

    // ---- one-time converts ----
    cast_bf16_kernel<<<(N * 128 / 4 + 255) / 256, blk, 0, stream>>>(x, xb, N * 128 / 4);
    wtrans_kernel<<<(256 * 128 + 255) / 256, blk, 0, stream>>>(enc_w1, enc1t, 128, 256, 256);
    wtrans_kernel<<<(128 * 256 + 255) / 256, blk, 0, stream>>>(enc_w2, enc2t, 256, 128, 128);
    for (int r = 0; r < R; ++r)
        wtrans_kernel<<<(128 * 128 + 255) / 256, blk, 0, stream>>>(
            gcn_w + (size_t)r * 128 * 128, gcnt + (size_t)r * 128 * 128, 128, 128, 128);
    wtrans_kernel<<<(128 * 128 + 255) / 256, blk, 0, stream>>>(dec_w1, dec1t, 128, 128, 128);
    wtrans_kernel<<<(48 * 128 + 255) / 256, blk, 0, stream>>>(dec_w2, dec2t, 128, 40, 48);

    // ---- CSR build ----
    const int nblkN = (N + 255) / 256;
    const int nblkE = (E + 255) / 256;
    hipMemsetAsync(cnt, 0, (size_t)N * sizeof(int), stream);
    degree_kernel<<<nblkE, blk, 0, stream>>>(dst, cnt, E);
    scan_block_kernel<<<nblkN, blk, 0, stream>>>(cnt, rs, partials, N);
    scan_partials_kernel<<<1, 512, 0, stream>>>(partials, nblkN);
    add_offsets_kernel<<<nblkN + 1, blk, 0, stream>>>(rs, partials, N, E);
    hipMemsetAsync(cnt, 0, (size_t)N * sizeof(int), stream);
    fill_kernel<<<nblkE, blk, 0, stream>>>(src, dst, rs, cnt, csr_src, E);

    // ---- dense grid: 4 waves x MR(2)*16 rows = 128 rows/block ----
    const int gdx = (N + 127) / 128;   // 782

    // encoder
    dense_mfma3_kernel<true, 2, 8, 128, false, true><<<dim3(gdx, 2), blk, 0, stream>>>(
        xb, enc1t, enc_b1, h1, N, 256);
    dense_mfma3_kernel<false, 2, 4, 256, false, true><<<dim3(gdx, 2), blk, 0, stream>>>(
        h1, enc2t, enc_b2, h, N, 128);

    // 3-hop GCN
    const int aggb = (N * 64 + 255) / 256;
    for (int r = 0; r < R; ++r) {
        dense_mfma3_kernel<false, 2, 8, 128, false, false><<<dim3(gdx, 1), blk, 0, stream>>>(
            h, gcnt + (size_t)r * 128 * 128, nullptr, hw, N, 128);
        gather_agg_kernel<<<aggb, blk, 0, stream>>>(
            hw, csr_src, rs, gcn_b + (size_t)r * 128, h, N);
    }

    // decoder
    dense_mfma3_kernel<true, 2, 8, 128, false, true><<<dim3(gdx, 1), blk, 0, stream>>>(
        h, dec1t, dec_b1, hw /*h2*/, N, 128);
    dense_mfma3_kernel<false, 2, 3, 128, true, true><<<dim3(gdx, 1), blk, 0, stream>>>(
        hw, dec2t, dec_b2, logits, N, 40);

    const int smb = (N + 3) / 4;
    log_softmax_kernel<<<smb, blk, 0, stream>>>(logits, out, N);
}

// Round 10
// 454.121 us; speedup vs baseline: 1.6193x; 1.0854x over previous
//
#include <hip/hip_runtime.h>
#include <hip/hip_bf16.h>
#include <cstddef>

typedef __attribute__((ext_vector_type(8))) short short8v;   // 8 x bf16 = 4 VGPR
typedef __attribute__((ext_vector_type(4))) float f32x4;     // MFMA accumulator

__device__ inline ushort f2bf(float f) {                     // f32 -> bf16 RNE
    uint u = __float_as_uint(f);
    uint r = (u + 0x7fffu + ((u >> 16) & 1u)) >> 16;
    return (ushort)r;
}
__device__ inline float bflo(uint v) { return __uint_as_float(v << 16); }
__device__ inline float bfhi(uint v) { return __uint_as_float(v & 0xffff0000u); }

// ---------------------------------------------------------------------------
// cast f32 -> bf16, 4 elements/thread
// ---------------------------------------------------------------------------
__global__ __launch_bounds__(256) void cast_bf16_kernel(
    const float* __restrict__ in, ushort* __restrict__ out, int n4)
{
    int i = blockIdx.x * 256 + threadIdx.x;
    if (i >= n4) return;
    float4 v = ((const float4*)in)[i];
    ushort4 o = { f2bf(v.x), f2bf(v.y), f2bf(v.z), f2bf(v.w) };
    ((ushort4*)out)[i] = o;
}

// ---------------------------------------------------------------------------
// W[K][Nout] f32  ->  Wt[rows][K] bf16  (rows >= Nout, zero-padded)
// ---------------------------------------------------------------------------
__global__ __launch_bounds__(256) void wtrans_kernel(
    const float* __restrict__ W, ushort* __restrict__ Wt,
    int K, int Nout, int rows)
{
    int idx = blockIdx.x * 256 + threadIdx.x;
    if (idx >= rows * K) return;
    int r = idx / K;
    int c = idx - r * K;
    float v = (r < Nout) ? W[(size_t)c * Nout + r] : 0.f;
    Wt[idx] = f2bf(v);
}

// ---------------------------------------------------------------------------
// bf16 MFMA dense v4: C[M,Ncols] = act(A[M,K] @ Wt^T + bias)
// 512 threads / 8 waves per block, MR=1 (16 rows/wave, 128 rows/blk).
// Same grid (782) but 2x resident waves/CU -> attacks the 22%-occupancy
// latency bound (R8 counters). LDS-staged swizzled weight tile + hoisted
// A-frags kept. Epilogue packs bf16 pairs via shfl -> 4B-aligned stores.
// ---------------------------------------------------------------------------
template <bool RELU, int NT, int KT, bool OUTF32, bool BIAS>
__global__ __launch_bounds__(512) void dense_mfma4_kernel(
    const ushort* __restrict__ A, const ushort* __restrict__ Wt,
    const float* __restrict__ bias, void* __restrict__ Cout,
    int M, int Ncols)
{
    constexpr int KSTEPS = KT / 32;
    constexpr int ROWS_B = NT * 16;
    constexpr int ROW_BYTES = KT * 2;
    constexpr int CHUNKS_PER_ROW = ROW_BYTES / 16;   // 16B chunks per row

    __shared__ __align__(16) char lds[ROWS_B * ROW_BYTES];

    const int tid  = threadIdx.x;
    const int lane = tid & 63;
    const int wave = tid >> 6;                       // 0..7
    const int fr   = lane & 15;
    const int fq   = lane >> 4;
    const int cb   = blockIdx.y * ROWS_B;            // weight-row (=col) base

    // ---- stage weight tile into LDS with XOR swizzle ----
    {
        constexpr int TOTAL = ROWS_B * CHUNKS_PER_ROW;
        #pragma unroll
        for (int c0 = 0; c0 < TOTAL; c0 += 512) {
            int c = c0 + tid;
            if (TOTAL % 512 != 0 && c >= TOTAL) break;
            int r = c / CHUNKS_PER_ROW;
            int w = c - r * CHUNKS_PER_ROW;
            short8v v = *(const short8v*)(Wt + (size_t)(cb + r) * KT + w * 8);
            int dstByte = r * ROW_BYTES + ((w * 16) ^ ((r & 7) << 4));
            *(short8v*)(lds + dstByte) = v;
        }
    }
    __syncthreads();

    const int rowblk = blockIdx.x * 128 + wave * 16;

    // ---- hoist all A fragments (streaming HBM read, paid once) ----
    short8v aReg[KSTEPS];
    {
        int r = rowblk + fr;
        if (r >= M) r = M - 1;
        #pragma unroll
        for (int ks = 0; ks < KSTEPS; ++ks)
            aReg[ks] = *(const short8v*)(A + (size_t)r * KT + ks * 32 + fq * 8);
    }

    f32x4 acc[NT];
    #pragma unroll
    for (int n = 0; n < NT; ++n) acc[n] = (f32x4){0.f, 0.f, 0.f, 0.f};

    // ---- MFMA loop: B from LDS, A from registers ----
    #pragma unroll
    for (int ks = 0; ks < KSTEPS; ++ks) {
        const int kByte = ks * 64 + fq * 16;
        short8v b[NT];
        #pragma unroll
        for (int n = 0; n < NT; ++n) {
            int lr = n * 16 + fr;
            b[n] = *(const short8v*)(lds + lr * ROW_BYTES + (kByte ^ ((lr & 7) << 4)));
        }
        #pragma unroll
        for (int n = 0; n < NT; ++n)
            acc[n] = __builtin_amdgcn_mfma_f32_16x16x32_bf16(aReg[ks], b[n], acc[n], 0, 0, 0);
    }

    // ---- epilogue ----
    float bv[NT];
    #pragma unroll
    for (int n = 0; n < NT; ++n) {
        int col = cb + n * 16 + fr;
        bv[n] = (BIAS && col < Ncols) ? bias[col] : 0.f;
    }
    const int rbase = rowblk + fq * 4;
    #pragma unroll
    for (int n = 0; n < NT; ++n) {
        int col = cb + n * 16 + fr;
        #pragma unroll
        for (int j = 0; j < 4; ++j) {
            int r = rbase + j;
            float v = acc[n][j] + bv[n];
            if (RELU) v = fmaxf(v, 0.f);
            if (OUTF32) {
                if (r < M && col < Ncols)
                    ((float*)Cout)[(size_t)r * Ncols + col] = v;
            } else {
                // pack neighbor-lane bf16 -> even lanes store aligned uint
                uint mybf = f2bf(v);
                uint nb   = (uint)__shfl_xor((int)mybf, 1, 64);
                if ((fr & 1) == 0 && r < M && col < Ncols) {
                    uint pk = (mybf & 0xffffu) | (nb << 16);
                    *(uint*)((ushort*)Cout + (size_t)r * Ncols + col) = pk;
                }
            }
        }
    }
}

// ---------------------------------------------------------------------------
// CSR build: histogram -> exclusive scan -> fill   (R4-verified)
// ---------------------------------------------------------------------------
__global__ __launch_bounds__(256) void degree_kernel(
    const int* __restrict__ dst, int* __restrict__ cnt, int E)
{
    int e = blockIdx.x * 256 + threadIdx.x;
    if (e < E) atomicAdd(&cnt[dst[e]], 1);
}

__global__ __launch_bounds__(256) void scan_block_kernel(
    const int* __restrict__ cnt, int* __restrict__ rs,
    int* __restrict__ partials, int N)
{
    __shared__ int sm[256];
    int i = blockIdx.x * 256 + threadIdx.x;
    int v = (i < N) ? cnt[i] : 0;
    sm[threadIdx.x] = v;
    __syncthreads();
    #pragma unroll
    for (int off = 1; off < 256; off <<= 1) {
        int t = (threadIdx.x >= off) ? sm[threadIdx.x - off] : 0;
        __syncthreads();
        sm[threadIdx.x] += t;
        __syncthreads();
    }
    if (i < N) rs[i] = sm[threadIdx.x] - v;
    if (threadIdx.x == 255) partials[blockIdx.x] = sm[255];
}

__global__ __launch_bounds__(512) void scan_partials_kernel(
    int* __restrict__ partials, int nblk)
{
    __shared__ int sm[512];
    int v = (threadIdx.x < nblk) ? partials[threadIdx.x] : 0;
    sm[threadIdx.x] = v;
    __syncthreads();
    #pragma unroll
    for (int off = 1; off < 512; off <<= 1) {
        int t = (threadIdx.x >= off) ? sm[threadIdx.x - off] : 0;
        __syncthreads();
        sm[threadIdx.x] += t;
        __syncthreads();
    }
    if (threadIdx.x < nblk) partials[threadIdx.x] = sm[threadIdx.x] - v;
}

__global__ __launch_bounds__(256) void add_offsets_kernel(
    int* __restrict__ rs, const int* __restrict__ partials, int N, int E)
{
    int i = blockIdx.x * 256 + threadIdx.x;
    if (i < N) rs[i] += partials[blockIdx.x];
    if (i == N) rs[N] = E;
}

__global__ __launch_bounds__(256) void fill_kernel(
    const int* __restrict__ src, const int* __restrict__ dst,
    const int* __restrict__ rs, int* __restrict__ cursor,
    int* __restrict__ csr_src, int E)
{
    int e = blockIdx.x * 256 + threadIdx.x;
    if (e >= E) return;
    int d = dst[e];
    int pos = rs[d] + atomicAdd(&cursor[d], 1);
    csr_src[pos] = src[e];
}

// ---------------------------------------------------------------------------
// hout[n] = relu( sum_{e in in(n)} hw[csr_src[e]] + bias )   bf16 I/O, f32 acc
// One wave/node, edge loop 4-deep unrolled (R8-verified).
// ---------------------------------------------------------------------------
__global__ __launch_bounds__(256) void gather_agg_kernel(
    const ushort* __restrict__ hw, const int* __restrict__ csr_src,
    const int* __restrict__ rs, const float* __restrict__ bias,
    ushort* __restrict__ hout, int N)
{
    int node = (blockIdx.x * 256 + threadIdx.x) >> 6;
    if (node >= N) return;
    int lane = threadIdx.x & 63;
    int beg = rs[node];
    int end = rs[node + 1];
    const size_t loff = (size_t)lane * 2;

    float ax = 0.f, ay = 0.f;
    int i = beg;
    for (; i + 4 <= end; i += 4) {
        int s0 = csr_src[i + 0];
        int s1 = csr_src[i + 1];
        int s2 = csr_src[i + 2];
        int s3 = csr_src[i + 3];
        uint v0 = *(const uint*)(hw + (size_t)s0 * 128 + loff);
        uint v1 = *(const uint*)(hw + (size_t)s1 * 128 + loff);
        uint v2 = *(const uint*)(hw + (size_t)s2 * 128 + loff);
        uint v3 = *(const uint*)(hw + (size_t)s3 * 128 + loff);
        ax += bflo(v0) + bflo(v1) + bflo(v2) + bflo(v3);
        ay += bfhi(v0) + bfhi(v1) + bfhi(v2) + bfhi(v3);
    }
    if (i + 2 <= end) {
        int s0 = csr_src[i + 0];
        int s1 = csr_src[i + 1];
        uint v0 = *(const uint*)(hw + (size_t)s0 * 128 + loff);
        uint v1 = *(const uint*)(hw + (size_t)s1 * 128 + loff);
        ax += bflo(v0) + bflo(v1);
        ay += bfhi(v0) + bfhi(v1);
        i += 2;
    }
    if (i < end) {
        int s0 = csr_src[i];
        uint v0 = *(const uint*)(hw + (size_t)s0 * 128 + loff);
        ax += bflo(v0);
        ay += bfhi(v0);
    }

    float2 b = *(const float2*)(bias + loff);
    ax = fmaxf(ax + b.x, 0.f);
    ay = fmaxf(ay + b.y, 0.f);
    uint o = (uint)f2bf(ax) | ((uint)f2bf(ay) << 16);
    *(uint*)(hout + (size_t)node * 128 + loff) = o;
}

// ---------------------------------------------------------------------------
// out = log_softmax(logits f32) over 40 cols, one wave per row
// ---------------------------------------------------------------------------
__global__ __launch_bounds__(256) void log_softmax_kernel(
    const float* __restrict__ logits, float* __restrict__ out, int M)
{
    int w    = (int)(((long long)blockIdx.x * 256 + threadIdx.x) >> 6);
    int lane = threadIdx.x & 63;
    if (w >= M) return;
    float v = -3.402823466e38f;
    if (lane < 40) v = logits[(size_t)w * 40 + lane];
    float m = v;
    #pragma unroll
    for (int off = 32; off > 0; off >>= 1) m = fmaxf(m, __shfl_xor(m, off, 64));
    float e = (lane < 40) ? expf(v - m) : 0.f;
    float s = e;
    #pragma unroll
    for (int off = 32; off > 0; off >>= 1) s += __shfl_xor(s, off, 64);
    float ls = logf(s);
    if (lane < 40) out[(size_t)w * 40 + lane] = v - m - ls;
}

// ---------------------------------------------------------------------------
extern "C" void kernel_launch(void* const* d_in, const int* in_sizes, int n_in,
                              void* d_out, int out_size, void* d_ws, size_t ws_size,
                              hipStream_t stream)
{
    const float* x      = (const float*)d_in[0];
    const int*   edge   = (const int*)d_in[1];
    const float* enc_w1 = (const float*)d_in[2];
    const float* enc_b1 = (const float*)d_in[3];
    const float* enc_w2 = (const float*)d_in[4];
    const float* enc_b2 = (const float*)d_in[5];
    const float* gcn_w  = (const float*)d_in[6];
    const float* gcn_b  = (const float*)d_in[7];
    const float* dec_w1 = (const float*)d_in[8];
    const float* dec_b1 = (const float*)d_in[9];
    const float* dec_w2 = (const float*)d_in[10];
    const float* dec_b2 = (const float*)d_in[11];

    const int F_IN = 128, H_ENC = 256, D = 128, N_CLS = 40, R = 3;
    const int N = in_sizes[0] / F_IN;   // 100000
    const int E = in_sizes[1] / 2;      // 600000
    const int* src = edge;
    const int* dst = edge + E;

    // ---- workspace layout (bytes) ----
    char* p = (char*)d_ws;
    ushort* xb     = (ushort*)p;                 p += (size_t)N * 128 * 2;
    ushort* h1     = (ushort*)p;                 p += (size_t)N * 256 * 2;
    ushort* h      = (ushort*)p;                 p += (size_t)N * 128 * 2;
    ushort* hw     = (ushort*)p;                 p += (size_t)N * 128 * 2;
    float*  logits = (float*)p;                  p += (size_t)N * 40 * 4;
    ushort* enc1t  = (ushort*)p;                 p += 256 * 128 * 2;
    ushort* enc2t  = (ushort*)p;                 p += 128 * 256 * 2;
    ushort* gcnt   = (ushort*)p;                 p += 3 * 128 * 128 * 2;
    ushort* dec1t  = (ushort*)p;                 p += 128 * 128 * 2;
    ushort* dec2t  = (ushort*)p;                 p += 48 * 128 * 2;
    int* csr_src   = (int*)p;
    int* rs        = csr_src + E;
    int* cnt       = rs + (N + 1);
    int* partials  = cnt + N;

    float* out = (float*)d_out;
    dim3 blk(256);
    dim3 blk512(512);

    // ---- one-time converts ----
    cast_bf16_kernel<<<(N * 128 / 4 + 255) / 256, blk, 0, stream>>>(x, xb, N * 128 / 4);
    wtrans_kernel<<<(256 * 128 + 255) / 256, blk, 0, stream>>>(enc_w1, enc1t, 128, 256, 256);
    wtrans_kernel<<<(128 * 256 + 255) / 256, blk, 0, stream>>>(enc_w2, enc2t, 256, 128, 128);
    for (int r = 0; r < R; ++r)
        wtrans_kernel<<<(128 * 128 + 255) / 256, blk, 0, stream>>>(
            gcn_w + (size_t)r * 128 * 128, gcnt + (size_t)r * 128 * 128, 128, 128, 128);
    wtrans_kernel<<<(128 * 128 + 255) / 256, blk, 0, stream>>>(dec_w1, dec1t, 128, 128, 128);
    wtrans_kernel<<<(48 * 128 + 255) / 256, blk, 0, stream>>>(dec_w2, dec2t, 128, 40, 48);

    // ---- CSR build ----
    const int nblkN = (N + 255) / 256;
    const int nblkE = (E + 255) / 256;
    hipMemsetAsync(cnt, 0, (size_t)N * sizeof(int), stream);
    degree_kernel<<<nblkE, blk, 0, stream>>>(dst, cnt, E);
    scan_block_kernel<<<nblkN, blk, 0, stream>>>(cnt, rs, partials, N);
    scan_partials_kernel<<<1, 512, 0, stream>>>(partials, nblkN);
    add_offsets_kernel<<<nblkN + 1, blk, 0, stream>>>(rs, partials, N, E);
    hipMemsetAsync(cnt, 0, (size_t)N * sizeof(int), stream);
    fill_kernel<<<nblkE, blk, 0, stream>>>(src, dst, rs, cnt, csr_src, E);

    // ---- dense grid: 8 waves x 16 rows = 128 rows/block ----
    const int gdx = (N + 127) / 128;   // 782

    // encoder
    dense_mfma4_kernel<true, 8, 128, false, true><<<dim3(gdx, 2), blk512, 0, stream>>>(
        xb, enc1t, enc_b1, h1, N, 256);
    dense_mfma4_kernel<false, 4, 256, false, true><<<dim3(gdx, 2), blk512, 0, stream>>>(
        h1, enc2t, enc_b2, h, N, 128);

    // 3-hop GCN
    const int aggb = (N * 64 + 255) / 256;
    for (int r = 0; r < R; ++r) {
        dense_mfma4_kernel<false, 8, 128, false, false><<<dim3(gdx, 1), blk512, 0, stream>>>(
            h, gcnt + (size_t)r * 128 * 128, nullptr, hw, N, 128);
        gather_agg_kernel<<<aggb, blk, 0, stream>>>(
            hw, csr_src, rs, gcn_b + (size_t)r * 128, h, N);
    }

    // decoder
    dense_mfma4_kernel<true, 8, 128, false, true><<<dim3(gdx, 1), blk512, 0, stream>>>(
        h, dec1t, dec_b1, hw /*h2*/, N, 128);
    dense_mfma4_kernel<false, 3, 128, true, true><<<dim3(gdx, 1), blk512, 0, stream>>>(
        hw, dec2t, dec_b2, logits, N, 40);

    const int smb = (N + 3) / 4;
    log_softmax_kernel<<<smb, blk, 0, stream>>>(logits, out, N);
}

// Round 11
// 414.343 us; speedup vs baseline: 1.7748x; 1.0960x over previous
//
#include <hip/hip_runtime.h>
#include <hip/hip_bf16.h>
#include <cstddef>

typedef __attribute__((ext_vector_type(8))) short short8v;   // 8 x bf16 = 4 VGPR
typedef __attribute__((ext_vector_type(4))) float f32x4;     // MFMA accumulator

__device__ inline ushort f2bf(float f) {                     // f32 -> bf16 RNE
    uint u = __float_as_uint(f);
    uint r = (u + 0x7fffu + ((u >> 16) & 1u)) >> 16;
    return (ushort)r;
}
__device__ inline float bflo(uint v) { return __uint_as_float(v << 16); }
__device__ inline float bfhi(uint v) { return __uint_as_float(v & 0xffff0000u); }

// ---------------------------------------------------------------------------
// cast f32 -> bf16, 4 elements/thread
// ---------------------------------------------------------------------------
__global__ __launch_bounds__(256) void cast_bf16_kernel(
    const float* __restrict__ in, ushort* __restrict__ out, int n4)
{
    int i = blockIdx.x * 256 + threadIdx.x;
    if (i >= n4) return;
    float4 v = ((const float4*)in)[i];
    ushort4 o = { f2bf(v.x), f2bf(v.y), f2bf(v.z), f2bf(v.w) };
    ((ushort4*)out)[i] = o;
}

// ---------------------------------------------------------------------------
// W[K][Nout] f32  ->  Wt[rows][K] bf16  (rows >= Nout, zero-padded)
// ---------------------------------------------------------------------------
__global__ __launch_bounds__(256) void wtrans_kernel(
    const float* __restrict__ W, ushort* __restrict__ Wt,
    int K, int Nout, int rows)
{
    int idx = blockIdx.x * 256 + threadIdx.x;
    if (idx >= rows * K) return;
    int r = idx / K;
    int c = idx - r * K;
    float v = (r < Nout) ? W[(size_t)c * Nout + r] : 0.f;
    Wt[idx] = f2bf(v);
}

// ---------------------------------------------------------------------------
// bf16 MFMA dense v5: C[M,Ncols] = act(A[M,K] @ Wt^T + bias)
// 512 threads / 8 waves, 16 rows/wave, 128 rows/block.
// R10->R11: LDS-transpose epilogue — acc tile goes through per-wave LDS
// scratch (reusing the weight buffer after a barrier) and is stored as
// full-line 16B/lane contiguous rows. Attacks the 2x write amplification
// (R8: WRITE 50MB for 25MB payload = partial-line RMW = the 42us).
// ---------------------------------------------------------------------------
template <bool RELU, int NT, int KT, bool OUTF32, bool BIAS>
__global__ __launch_bounds__(512) void dense_mfma5_kernel(
    const ushort* __restrict__ A, const ushort* __restrict__ Wt,
    const float* __restrict__ bias, void* __restrict__ Cout,
    int M, int Ncols)
{
    constexpr int KSTEPS = KT / 32;
    constexpr int ROWS_B = NT * 16;
    constexpr int ROW_BYTES = KT * 2;
    constexpr int CHUNKS_PER_ROW = ROW_BYTES / 16;   // 16B chunks per row

    // weight tile; reused post-barrier as epilogue scratch (8 waves * NT*512B
    // <= ROWS_B*ROW_BYTES for KT>=128)
    __shared__ __align__(16) char lds[ROWS_B * ROW_BYTES];

    const int tid  = threadIdx.x;
    const int lane = tid & 63;
    const int wave = tid >> 6;                       // 0..7
    const int fr   = lane & 15;
    const int fq   = lane >> 4;
    const int cb   = blockIdx.y * ROWS_B;            // weight-row (=col) base

    // ---- stage weight tile into LDS with XOR swizzle ----
    {
        constexpr int TOTAL = ROWS_B * CHUNKS_PER_ROW;
        #pragma unroll
        for (int c0 = 0; c0 < TOTAL; c0 += 512) {
            int c = c0 + tid;
            if (TOTAL % 512 != 0 && c >= TOTAL) break;
            int r = c / CHUNKS_PER_ROW;
            int w = c - r * CHUNKS_PER_ROW;
            short8v v = *(const short8v*)(Wt + (size_t)(cb + r) * KT + w * 8);
            int dstByte = r * ROW_BYTES + ((w * 16) ^ ((r & 7) << 4));
            *(short8v*)(lds + dstByte) = v;
        }
    }
    __syncthreads();

    const int rowblk = blockIdx.x * 128 + wave * 16;

    // ---- hoist all A fragments ----
    short8v aReg[KSTEPS];
    {
        int r = rowblk + fr;
        if (r >= M) r = M - 1;
        #pragma unroll
        for (int ks = 0; ks < KSTEPS; ++ks)
            aReg[ks] = *(const short8v*)(A + (size_t)r * KT + ks * 32 + fq * 8);
    }

    f32x4 acc[NT];
    #pragma unroll
    for (int n = 0; n < NT; ++n) acc[n] = (f32x4){0.f, 0.f, 0.f, 0.f};

    // ---- MFMA loop: B from LDS, A from registers ----
    #pragma unroll
    for (int ks = 0; ks < KSTEPS; ++ks) {
        const int kByte = ks * 64 + fq * 16;
        short8v b[NT];
        #pragma unroll
        for (int n = 0; n < NT; ++n) {
            int lr = n * 16 + fr;
            b[n] = *(const short8v*)(lds + lr * ROW_BYTES + (kByte ^ ((lr & 7) << 4)));
        }
        #pragma unroll
        for (int n = 0; n < NT; ++n)
            acc[n] = __builtin_amdgcn_mfma_f32_16x16x32_bf16(aReg[ks], b[n], acc[n], 0, 0, 0);
    }

    // ---- bias ----
    float bv[NT];
    #pragma unroll
    for (int n = 0; n < NT; ++n) {
        int col = cb + n * 16 + fr;
        bv[n] = (BIAS && col < Ncols) ? bias[col] : 0.f;
    }

    if constexpr (!OUTF32) {
        // ---- LDS-transpose epilogue: full-line coalesced bf16 stores ----
        __syncthreads();                             // weights dead everywhere
        constexpr int SROW = NT * 32;                // bytes/row in scratch
        char* scratch = lds + wave * (16 * SROW);
        #pragma unroll
        for (int n = 0; n < NT; ++n) {
            #pragma unroll
            for (int j = 0; j < 4; ++j) {
                int row = fq * 4 + j;
                float v = acc[n][j] + bv[n];
                if (RELU) v = fmaxf(v, 0.f);
                int byte = (n * 32 + fr * 2) ^ ((row & 3) << 5);
                *(ushort*)(scratch + row * SROW + byte) = f2bf(v);
            }
        }
        // per-wave private scratch: no barrier needed, lgkmcnt ordering only
        constexpr int LPR = 2 * NT;                  // lanes per row (16B each)
        constexpr int RPI = 64 / LPR;                // rows per instr
        constexpr int NI  = 16 / RPI;                // instrs
        #pragma unroll
        for (int i2 = 0; i2 < NI; ++i2) {
            int row = i2 * RPI + lane / LPR;
            int k16 = lane % LPR;
            int rb  = row * SROW + ((k16 * 16) ^ ((row & 3) << 5));
            short8v vv = *(const short8v*)(scratch + rb);
            int gr = rowblk + row;
            if (gr < M)
                *(short8v*)((char*)Cout + (size_t)gr * (Ncols * 2) + cb * 2 + k16 * 16) = vv;
        }
    } else {
        // f32 scalar path (dec2 logits, Ncols=40)
        const int rbase = rowblk + fq * 4;
        #pragma unroll
        for (int n = 0; n < NT; ++n) {
            int col = cb + n * 16 + fr;
            #pragma unroll
            for (int j = 0; j < 4; ++j) {
                int r = rbase + j;
                float v = acc[n][j] + bv[n];
                if (RELU) v = fmaxf(v, 0.f);
                if (r < M && col < Ncols)
                    ((float*)Cout)[(size_t)r * Ncols + col] = v;
            }
        }
    }
}

// ---------------------------------------------------------------------------
// CSR build: histogram -> exclusive scan -> fill   (R4-verified)
// ---------------------------------------------------------------------------
__global__ __launch_bounds__(256) void degree_kernel(
    const int* __restrict__ dst, int* __restrict__ cnt, int E)
{
    int e = blockIdx.x * 256 + threadIdx.x;
    if (e < E) atomicAdd(&cnt[dst[e]], 1);
}

__global__ __launch_bounds__(256) void scan_block_kernel(
    const int* __restrict__ cnt, int* __restrict__ rs,
    int* __restrict__ partials, int N)
{
    __shared__ int sm[256];
    int i = blockIdx.x * 256 + threadIdx.x;
    int v = (i < N) ? cnt[i] : 0;
    sm[threadIdx.x] = v;
    __syncthreads();
    #pragma unroll
    for (int off = 1; off < 256; off <<= 1) {
        int t = (threadIdx.x >= off) ? sm[threadIdx.x - off] : 0;
        __syncthreads();
        sm[threadIdx.x] += t;
        __syncthreads();
    }
    if (i < N) rs[i] = sm[threadIdx.x] - v;
    if (threadIdx.x == 255) partials[blockIdx.x] = sm[255];
}

__global__ __launch_bounds__(512) void scan_partials_kernel(
    int* __restrict__ partials, int nblk)
{
    __shared__ int sm[512];
    int v = (threadIdx.x < nblk) ? partials[threadIdx.x] : 0;
    sm[threadIdx.x] = v;
    __syncthreads();
    #pragma unroll
    for (int off = 1; off < 512; off <<= 1) {
        int t = (threadIdx.x >= off) ? sm[threadIdx.x - off] : 0;
        __syncthreads();
        sm[threadIdx.x] += t;
        __syncthreads();
    }
    if (threadIdx.x < nblk) partials[threadIdx.x] = sm[threadIdx.x] - v;
}

__global__ __launch_bounds__(256) void add_offsets_kernel(
    int* __restrict__ rs, const int* __restrict__ partials, int N, int E)
{
    int i = blockIdx.x * 256 + threadIdx.x;
    if (i < N) rs[i] += partials[blockIdx.x];
    if (i == N) rs[N] = E;
}

__global__ __launch_bounds__(256) void fill_kernel(
    const int* __restrict__ src, const int* __restrict__ dst,
    const int* __restrict__ rs, int* __restrict__ cursor,
    int* __restrict__ csr_src, int E)
{
    int e = blockIdx.x * 256 + threadIdx.x;
    if (e >= E) return;
    int d = dst[e];
    int pos = rs[d] + atomicAdd(&cursor[d], 1);
    csr_src[pos] = src[e];
}

// ---------------------------------------------------------------------------
// gather-agg v2: 2 nodes per wave (half-wave = 32 lanes x uint2 = 256B row).
// Halves wave count and overlaps two nodes' dependent-load chains (R10:
// latency-bound at VALU 31% / HBM 30%). Edge loop 4-deep unrolled.
// ---------------------------------------------------------------------------
__global__ __launch_bounds__(256) void gather_agg2_kernel(
    const ushort* __restrict__ hw, const int* __restrict__ csr_src,
    const int* __restrict__ rs, const float* __restrict__ bias,
    ushort* __restrict__ hout, int N)
{
    int wid  = (blockIdx.x * 256 + threadIdx.x) >> 6;
    int lane = threadIdx.x & 63;
    int node = wid * 2 + (lane >> 5);
    if (node >= N) return;
    int sl = lane & 31;
    int beg = rs[node];
    int end = rs[node + 1];

    float a0 = 0.f, a1 = 0.f, a2 = 0.f, a3 = 0.f;
    int i = beg;
    for (; i + 4 <= end; i += 4) {
        int s0 = csr_src[i + 0];
        int s1 = csr_src[i + 1];
        int s2 = csr_src[i + 2];
        int s3 = csr_src[i + 3];
        uint2 v0 = *(const uint2*)(hw + (size_t)s0 * 128 + sl * 4);
        uint2 v1 = *(const uint2*)(hw + (size_t)s1 * 128 + sl * 4);
        uint2 v2 = *(const uint2*)(hw + (size_t)s2 * 128 + sl * 4);
        uint2 v3 = *(const uint2*)(hw + (size_t)s3 * 128 + sl * 4);
        a0 += bflo(v0.x) + bflo(v1.x) + bflo(v2.x) + bflo(v3.x);
        a1 += bfhi(v0.x) + bfhi(v1.x) + bfhi(v2.x) + bfhi(v3.x);
        a2 += bflo(v0.y) + bflo(v1.y) + bflo(v2.y) + bflo(v3.y);
        a3 += bfhi(v0.y) + bfhi(v1.y) + bfhi(v2.y) + bfhi(v3.y);
    }
    if (i + 2 <= end) {
        int s0 = csr_src[i + 0];
        int s1 = csr_src[i + 1];
        uint2 v0 = *(const uint2*)(hw + (size_t)s0 * 128 + sl * 4);
        uint2 v1 = *(const uint2*)(hw + (size_t)s1 * 128 + sl * 4);
        a0 += bflo(v0.x) + bflo(v1.x);
        a1 += bfhi(v0.x) + bfhi(v1.x);
        a2 += bflo(v0.y) + bflo(v1.y);
        a3 += bfhi(v0.y) + bfhi(v1.y);
        i += 2;
    }
    if (i < end) {
        int s0 = csr_src[i];
        uint2 v0 = *(const uint2*)(hw + (size_t)s0 * 128 + sl * 4);
        a0 += bflo(v0.x);
        a1 += bfhi(v0.x);
        a2 += bflo(v0.y);
        a3 += bfhi(v0.y);
    }

    float4 bb = ((const float4*)bias)[sl];
    a0 = fmaxf(a0 + bb.x, 0.f);
    a1 = fmaxf(a1 + bb.y, 0.f);
    a2 = fmaxf(a2 + bb.z, 0.f);
    a3 = fmaxf(a3 + bb.w, 0.f);
    uint2 o;
    o.x = (uint)f2bf(a0) | ((uint)f2bf(a1) << 16);
    o.y = (uint)f2bf(a2) | ((uint)f2bf(a3) << 16);
    *(uint2*)(hout + (size_t)node * 128 + sl * 4) = o;
}

// ---------------------------------------------------------------------------
// out = log_softmax(logits f32) over 40 cols, one wave per row
// ---------------------------------------------------------------------------
__global__ __launch_bounds__(256) void log_softmax_kernel(
    const float* __restrict__ logits, float* __restrict__ out, int M)
{
    int w    = (int)(((long long)blockIdx.x * 256 + threadIdx.x) >> 6);
    int lane = threadIdx.x & 63;
    if (w >= M) return;
    float v = -3.402823466e38f;
    if (lane < 40) v = logits[(size_t)w * 40 + lane];
    float m = v;
    #pragma unroll
    for (int off = 32; off > 0; off >>= 1) m = fmaxf(m, __shfl_xor(m, off, 64));
    float e = (lane < 40) ? expf(v - m) : 0.f;
    float s = e;
    #pragma unroll
    for (int off = 32; off > 0; off >>= 1) s += __shfl_xor(s, off, 64);
    float ls = logf(s);
    if (lane < 40) out[(size_t)w * 40 + lane] = v - m - ls;
}

// ---------------------------------------------------------------------------
extern "C" void kernel_launch(void* const* d_in, const int* in_sizes, int n_in,
                              void* d_out, int out_size, void* d_ws, size_t ws_size,
                              hipStream_t stream)
{
    const float* x      = (const float*)d_in[0];
    const int*   edge   = (const int*)d_in[1];
    const float* enc_w1 = (const float*)d_in[2];
    const float* enc_b1 = (const float*)d_in[3];
    const float* enc_w2 = (const float*)d_in[4];
    const float* enc_b2 = (const float*)d_in[5];
    const float* gcn_w  = (const float*)d_in[6];
    const float* gcn_b  = (const float*)d_in[7];
    const float* dec_w1 = (const float*)d_in[8];
    const float* dec_b1 = (const float*)d_in[9];
    const float* dec_w2 = (const float*)d_in[10];
    const float* dec_b2 = (const float*)d_in[11];

    const int F_IN = 128, H_ENC = 256, D = 128, N_CLS = 40, R = 3;
    const int N = in_sizes[0] / F_IN;   // 100000
    const int E = in_sizes[1] / 2;      // 600000
    const int* src = edge;
    const int* dst = edge + E;

    // ---- workspace layout (bytes) ----
    char* p = (char*)d_ws;
    ushort* xb     = (ushort*)p;                 p += (size_t)N * 128 * 2;
    ushort* h1     = (ushort*)p;                 p += (size_t)N * 256 * 2;
    ushort* h      = (ushort*)p;                 p += (size_t)N * 128 * 2;
    ushort* hw     = (ushort*)p;                 p += (size_t)N * 128 * 2;
    float*  logits = (float*)p;                  p += (size_t)N * 40 * 4;
    ushort* enc1t  = (ushort*)p;                 p += 256 * 128 * 2;
    ushort* enc2t  = (ushort*)p;                 p += 128 * 256 * 2;
    ushort* gcnt   = (ushort*)p;                 p += 3 * 128 * 128 * 2;
    ushort* dec1t  = (ushort*)p;                 p += 128 * 128 * 2;
    ushort* dec2t  = (ushort*)p;                 p += 48 * 128 * 2;
    int* csr_src   = (int*)p;
    int* rs        = csr_src + E;
    int* cnt       = rs + (N + 1);
    int* partials  = cnt + N;

    float* out = (float*)d_out;
    dim3 blk(256);
    dim3 blk512(512);

    // ---- one-time converts ----
    cast_bf16_kernel<<<(N * 128 / 4 + 255) / 256, blk, 0, stream>>>(x, xb, N * 128 / 4);
    wtrans_kernel<<<(256 * 128 + 255) / 256, blk, 0, stream>>>(enc_w1, enc1t, 128, 256, 256);
    wtrans_kernel<<<(128 * 256 + 255) / 256, blk, 0, stream>>>(enc_w2, enc2t, 256, 128, 128);
    for (int r = 0; r < R; ++r)
        wtrans_kernel<<<(128 * 128 + 255) / 256, blk, 0, stream>>>(
            gcn_w + (size_t)r * 128 * 128, gcnt + (size_t)r * 128 * 128, 128, 128, 128);
    wtrans_kernel<<<(128 * 128 + 255) / 256, blk, 0, stream>>>(dec_w1, dec1t, 128, 128, 128);
    wtrans_kernel<<<(48 * 128 + 255) / 256, blk, 0, stream>>>(dec_w2, dec2t, 128, 40, 48);

    // ---- CSR build ----
    const int nblkN = (N + 255) / 256;
    const int nblkE = (E + 255) / 256;
    hipMemsetAsync(cnt, 0, (size_t)N * sizeof(int), stream);
    degree_kernel<<<nblkE, blk, 0, stream>>>(dst, cnt, E);
    scan_block_kernel<<<nblkN, blk, 0, stream>>>(cnt, rs, partials, N);
    scan_partials_kernel<<<1, 512, 0, stream>>>(partials, nblkN);
    add_offsets_kernel<<<nblkN + 1, blk, 0, stream>>>(rs, partials, N, E);
    hipMemsetAsync(cnt, 0, (size_t)N * sizeof(int), stream);
    fill_kernel<<<nblkE, blk, 0, stream>>>(src, dst, rs, cnt, csr_src, E);

    // ---- dense grid: 8 waves x 16 rows = 128 rows/block ----
    const int gdx = (N + 127) / 128;   // 782

    // encoder
    dense_mfma5_kernel<true, 8, 128, false, true><<<dim3(gdx, 2), blk512, 0, stream>>>(
        xb, enc1t, enc_b1, h1, N, 256);
    dense_mfma5_kernel<false, 4, 256, false, true><<<dim3(gdx, 2), blk512, 0, stream>>>(
        h1, enc2t, enc_b2, h, N, 128);

    // 3-hop GCN
    const int aggb = ((N + 1) / 2 * 64 + 255) / 256;   // 2 nodes per wave
    for (int r = 0; r < R; ++r) {
        dense_mfma5_kernel<false, 8, 128, false, false><<<dim3(gdx, 1), blk512, 0, stream>>>(
            h, gcnt + (size_t)r * 128 * 128, nullptr, hw, N, 128);
        gather_agg2_kernel<<<aggb, blk, 0, stream>>>(
            hw, csr_src, rs, gcn_b + (size_t)r * 128, h, N);
    }

    // decoder
    dense_mfma5_kernel<true, 8, 128, false, true><<<dim3(gdx, 1), blk512, 0, stream>>>(
        h, dec1t, dec_b1, hw /*h2*/, N, 128);
    dense_mfma5_kernel<false, 3, 128, true, true><<<dim3(gdx, 1), blk512, 0, stream>>>(
        hw, dec2t, dec_b2, logits, N, 40);

    const int smb = (N + 3) / 4;
    log_softmax_kernel<<<smb, blk, 0, stream>>>(logits, out, N);
}

// Round 13
// 365.597 us; speedup vs baseline: 2.0114x; 1.1333x over previous
//
#include <hip/hip_runtime.h>
#include <hip/hip_bf16.h>
#include <cstddef>

typedef __attribute__((ext_vector_type(8))) short short8v;   // 8 x bf16 = 4 VGPR
typedef __attribute__((ext_vector_type(4))) float f32x4;     // MFMA accumulator

__device__ inline ushort f2bf(float f) {                     // f32 -> bf16 RNE
    uint u = __float_as_uint(f);
    uint r = (u + 0x7fffu + ((u >> 16) & 1u)) >> 16;
    return (ushort)r;
}
__device__ inline float bflo(uint v) { return __uint_as_float(v << 16); }
__device__ inline float bfhi(uint v) { return __uint_as_float(v & 0xffff0000u); }

// ---------------------------------------------------------------------------
// All 6 weight transposes in ONE dispatch (blockIdx.y selects the weight).
// W[K][Nout] f32 -> arena[dst + r*K + c] bf16, rows zero-padded.
// arena elem offsets: enc1t=0(256x128) enc2t=32768(128x256) gcn=65536+r*16384
// dec1t=114688(128x128) dec2t=131072(48x128)
// ---------------------------------------------------------------------------
__global__ __launch_bounds__(256) void wtrans_all_kernel(
    const float* __restrict__ w1, const float* __restrict__ w2,
    const float* __restrict__ gw, const float* __restrict__ d1,
    const float* __restrict__ d2, ushort* __restrict__ arena)
{
    const int y = blockIdx.y;
    const float* W; int K, Nout, rows; size_t dst;
    switch (y) {
        case 0: W = w1; K = 128; Nout = 256; rows = 256; dst = 0;      break;
        case 1: W = w2; K = 256; Nout = 128; rows = 128; dst = 32768;  break;
        case 2: case 3: case 4:
            W = gw + (size_t)(y - 2) * 16384; K = 128; Nout = 128; rows = 128;
            dst = 65536 + (size_t)(y - 2) * 16384;                     break;
        case 5: W = d1; K = 128; Nout = 128; rows = 128; dst = 114688; break;
        default: W = d2; K = 128; Nout = 40; rows = 48; dst = 131072;  break;
    }
    int idx = blockIdx.x * 256 + threadIdx.x;
    if (idx >= rows * K) return;
    int r = idx / K;
    int c = idx - r * K;
    float v = (r < Nout) ? W[(size_t)c * Nout + r] : 0.f;
    arena[dst + idx] = f2bf(v);
}

// ---------------------------------------------------------------------------
// bf16 MFMA dense: C[M,Ncols](bf16) = act(A[M,KT] @ Wt^T + bias)
// 512 thr / 8 waves, 16 rows/wave. LDS-staged swizzled weights, hoisted
// A-frags, LDS-transpose full-line epilogue (all R11-verified).
// AF32: A is f32, converted in-register (kills the cast pass).
// ---------------------------------------------------------------------------
template <bool RELU, int NT, int KT, bool AF32, bool BIAS>
__global__ __launch_bounds__(512) void dense_mfma5_kernel(
    const void* __restrict__ A, const ushort* __restrict__ Wt,
    const float* __restrict__ bias, ushort* __restrict__ Cout,
    int M, int Ncols)
{
    constexpr int KSTEPS = KT / 32;
    constexpr int ROWS_B = NT * 16;
    constexpr int ROW_BYTES = KT * 2;
    constexpr int CHUNKS_PER_ROW = ROW_BYTES / 16;

    __shared__ __align__(16) char lds[ROWS_B * ROW_BYTES];

    const int tid  = threadIdx.x;
    const int lane = tid & 63;
    const int wave = tid >> 6;
    const int fr   = lane & 15;
    const int fq   = lane >> 4;
    const int cb   = blockIdx.y * ROWS_B;

    {   // stage weight tile, XOR-swizzled
        constexpr int TOTAL = ROWS_B * CHUNKS_PER_ROW;
        #pragma unroll
        for (int c0 = 0; c0 < TOTAL; c0 += 512) {
            int c = c0 + tid;
            if (TOTAL % 512 != 0 && c >= TOTAL) break;
            int r = c / CHUNKS_PER_ROW;
            int w = c - r * CHUNKS_PER_ROW;
            short8v v = *(const short8v*)(Wt + (size_t)(cb + r) * KT + w * 8);
            int dstByte = r * ROW_BYTES + ((w * 16) ^ ((r & 7) << 4));
            *(short8v*)(lds + dstByte) = v;
        }
    }
    __syncthreads();

    const int rowblk = blockIdx.x * 128 + wave * 16;

    short8v aReg[KSTEPS];
    {
        int r = rowblk + fr;
        if (r >= M) r = M - 1;
        if constexpr (AF32) {
            const float* Af = (const float*)A;
            #pragma unroll
            for (int ks = 0; ks < KSTEPS; ++ks) {
                float4 p0 = *(const float4*)(Af + (size_t)r * KT + ks * 32 + fq * 8);
                float4 p1 = *(const float4*)(Af + (size_t)r * KT + ks * 32 + fq * 8 + 4);
                short8v o;
                o[0] = (short)f2bf(p0.x); o[1] = (short)f2bf(p0.y);
                o[2] = (short)f2bf(p0.z); o[3] = (short)f2bf(p0.w);
                o[4] = (short)f2bf(p1.x); o[5] = (short)f2bf(p1.y);
                o[6] = (short)f2bf(p1.z); o[7] = (short)f2bf(p1.w);
                aReg[ks] = o;
            }
        } else {
            const ushort* Ab = (const ushort*)A;
            #pragma unroll
            for (int ks = 0; ks < KSTEPS; ++ks)
                aReg[ks] = *(const short8v*)(Ab + (size_t)r * KT + ks * 32 + fq * 8);
        }
    }

    f32x4 acc[NT];
    #pragma unroll
    for (int n = 0; n < NT; ++n) acc[n] = (f32x4){0.f, 0.f, 0.f, 0.f};

    #pragma unroll
    for (int ks = 0; ks < KSTEPS; ++ks) {
        const int kByte = ks * 64 + fq * 16;
        short8v b[NT];
        #pragma unroll
        for (int n = 0; n < NT; ++n) {
            int lr = n * 16 + fr;
            b[n] = *(const short8v*)(lds + lr * ROW_BYTES + (kByte ^ ((lr & 7) << 4)));
        }
        #pragma unroll
        for (int n = 0; n < NT; ++n)
            acc[n] = __builtin_amdgcn_mfma_f32_16x16x32_bf16(aReg[ks], b[n], acc[n], 0, 0, 0);
    }

    float bv[NT];
    #pragma unroll
    for (int n = 0; n < NT; ++n) {
        int col = cb + n * 16 + fr;
        bv[n] = (BIAS && col < Ncols) ? bias[col] : 0.f;
    }

    // LDS-transpose epilogue -> full-line bf16 stores
    __syncthreads();
    constexpr int SROW = NT * 32;
    char* scratch = lds + wave * (16 * SROW);
    #pragma unroll
    for (int n = 0; n < NT; ++n) {
        #pragma unroll
        for (int j = 0; j < 4; ++j) {
            int row = fq * 4 + j;
            float v = acc[n][j] + bv[n];
            if (RELU) v = fmaxf(v, 0.f);
            int byte = (n * 32 + fr * 2) ^ ((row & 3) << 5);
            *(ushort*)(scratch + row * SROW + byte) = f2bf(v);
        }
    }
    constexpr int LPR = 2 * NT;
    constexpr int RPI = 64 / LPR;
    constexpr int NI  = 16 / RPI;
    #pragma unroll
    for (int i2 = 0; i2 < NI; ++i2) {
        int row = i2 * RPI + lane / LPR;
        int k16 = lane % LPR;
        int rb  = row * SROW + ((k16 * 16) ^ ((row & 3) << 5));
        short8v vv = *(const short8v*)(scratch + rb);
        int gr = rowblk + row;
        if (gr < M)
            *(short8v*)((char*)Cout + (size_t)gr * (Ncols * 2) + cb * 2 + k16 * 16) = vv;
    }
}

// ---------------------------------------------------------------------------
// Fused GCN hop: hout = relu( (sum_{nbr} h[src]) @ W + bias )
// (linearity: sum(h[src]@W) == (sum h[src])@W). Gather in f32, convert,
// then MFMA from the LDS-staged weight tile. 16 nodes/wave, 4 lanes/node,
// 16B loads (4 independent per neighbor -> MLP). Saves the hw round-trip
// and one dispatch per hop.
// ---------------------------------------------------------------------------
__global__ __launch_bounds__(512, 4) void gcn_hop_kernel(
    const ushort* __restrict__ h, const ushort* __restrict__ Wt,
    const int* __restrict__ csr_src, const int* __restrict__ rs,
    const float* __restrict__ bias, ushort* __restrict__ hout, int N)
{
    constexpr int NT = 8, KT = 128, KSTEPS = 4;
    constexpr int ROWS_B = 128, ROW_BYTES = 256, CHUNKS_PER_ROW = 16;

    __shared__ __align__(16) char lds[ROWS_B * ROW_BYTES];   // 32 KB

    const int tid  = threadIdx.x;
    const int lane = tid & 63;
    const int wave = tid >> 6;
    const int fr   = lane & 15;
    const int fq   = lane >> 4;

    {   // stage weight tile (issue early; barrier comes after the gather)
        constexpr int TOTAL = ROWS_B * CHUNKS_PER_ROW;   // 2048
        #pragma unroll
        for (int c0 = 0; c0 < TOTAL; c0 += 512) {
            int c = c0 + tid;
            int r = c / CHUNKS_PER_ROW;
            int w = c - r * CHUNKS_PER_ROW;
            short8v v = *(const short8v*)(Wt + (size_t)r * KT + w * 8);
            int dstByte = r * ROW_BYTES + ((w * 16) ^ ((r & 7) << 4));
            *(short8v*)(lds + dstByte) = v;
        }
    }

    const int rowblk = blockIdx.x * 128 + wave * 16;
    const int node   = rowblk + fr;
    int beg = 0, end = 0;
    if (node < N) { beg = rs[node]; end = rs[node + 1]; }

    float sf[KSTEPS][8];
    #pragma unroll
    for (int ks = 0; ks < KSTEPS; ++ks)
        #pragma unroll
        for (int e = 0; e < 8; ++e) sf[ks][e] = 0.f;

    int i = beg;
    for (; i + 2 <= end; i += 2) {            // 2 neighbors -> 8 loads in flight
        int s0 = csr_src[i + 0];
        int s1 = csr_src[i + 1];
        const ushort* h0 = h + (size_t)s0 * 128;
        const ushort* h1 = h + (size_t)s1 * 128;
        #pragma unroll
        for (int ks = 0; ks < KSTEPS; ++ks) {
            uint4 q0 = *(const uint4*)(h0 + ks * 32 + fq * 8);
            uint4 q1 = *(const uint4*)(h1 + ks * 32 + fq * 8);
            sf[ks][0] += bflo(q0.x) + bflo(q1.x);
            sf[ks][1] += bfhi(q0.x) + bfhi(q1.x);
            sf[ks][2] += bflo(q0.y) + bflo(q1.y);
            sf[ks][3] += bfhi(q0.y) + bfhi(q1.y);
            sf[ks][4] += bflo(q0.z) + bflo(q1.z);
            sf[ks][5] += bfhi(q0.z) + bfhi(q1.z);
            sf[ks][6] += bflo(q0.w) + bflo(q1.w);
            sf[ks][7] += bfhi(q0.w) + bfhi(q1.w);
        }
    }
    if (i < end) {
        int s0 = csr_src[i];
        const ushort* h0 = h + (size_t)s0 * 128;
        #pragma unroll
        for (int ks = 0; ks < KSTEPS; ++ks) {
            uint4 q0 = *(const uint4*)(h0 + ks * 32 + fq * 8);
            sf[ks][0] += bflo(q0.x); sf[ks][1] += bfhi(q0.x);
            sf[ks][2] += bflo(q0.y); sf[ks][3] += bfhi(q0.y);
            sf[ks][4] += bflo(q0.z); sf[ks][5] += bfhi(q0.z);
            sf[ks][6] += bflo(q0.w); sf[ks][7] += bfhi(q0.w);
        }
    }

    short8v aReg[KSTEPS];
    #pragma unroll
    for (int ks = 0; ks < KSTEPS; ++ks) {
        short8v o;
        #pragma unroll
        for (int e = 0; e < 8; ++e) o[e] = (short)f2bf(sf[ks][e]);
        aReg[ks] = o;
    }

    f32x4 acc[NT];
    #pragma unroll
    for (int n = 0; n < NT; ++n) acc[n] = (f32x4){0.f, 0.f, 0.f, 0.f};

    __syncthreads();                          // weights staged

    #pragma unroll
    for (int ks = 0; ks < KSTEPS; ++ks) {
        const int kByte = ks * 64 + fq * 16;
        short8v b[NT];
        #pragma unroll
        for (int n = 0; n < NT; ++n) {
            int lr = n * 16 + fr;
            b[n] = *(const short8v*)(lds + lr * ROW_BYTES + (kByte ^ ((lr & 7) << 4)));
        }
        #pragma unroll
        for (int n = 0; n < NT; ++n)
            acc[n] = __builtin_amdgcn_mfma_f32_16x16x32_bf16(aReg[ks], b[n], acc[n], 0, 0, 0);
    }

    float bv[NT];
    #pragma unroll
    for (int n = 0; n < NT; ++n) bv[n] = bias[n * 16 + fr];

    __syncthreads();                          // weights dead -> scratch reuse
    constexpr int SROW = NT * 32;             // 256 B
    char* scratch = lds + wave * (16 * SROW);
    #pragma unroll
    for (int n = 0; n < NT; ++n) {
        #pragma unroll
        for (int j = 0; j < 4; ++j) {
            int row = fq * 4 + j;
            float v = fmaxf(acc[n][j] + bv[n], 0.f);
            int byte = (n * 32 + fr * 2) ^ ((row & 3) << 5);
            *(ushort*)(scratch + row * SROW + byte) = f2bf(v);
        }
    }
    constexpr int LPR = 16, RPI = 4, NI = 4;
    #pragma unroll
    for (int i2 = 0; i2 < NI; ++i2) {
        int row = i2 * RPI + lane / LPR;
        int k16 = lane % LPR;
        int rb  = row * SROW + ((k16 * 16) ^ ((row & 3) << 5));
        short8v vv = *(const short8v*)(scratch + rb);
        int gr = rowblk + row;
        if (gr < N)
            *(short8v*)((char*)hout + (size_t)gr * 256 + k16 * 16) = vv;
    }
}

// ---------------------------------------------------------------------------
// dec2 + log_softmax fused: out[M,40] = log_softmax(A @ Wt^T + bias)
// NT=3, KT=128. Softmax over each row's 40 cols via 16-lane shfl reduce.
// ---------------------------------------------------------------------------
__global__ __launch_bounds__(512) void dense_dec2sm_kernel(
    const ushort* __restrict__ A, const ushort* __restrict__ Wt,
    const float* __restrict__ bias, float* __restrict__ out, int M)
{
    constexpr int NT = 3, KT = 128, KSTEPS = 4;
    constexpr int ROWS_B = 48, ROW_BYTES = 256, CHUNKS_PER_ROW = 16;

    __shared__ __align__(16) char lds[ROWS_B * ROW_BYTES];   // 12 KB

    const int tid  = threadIdx.x;
    const int lane = tid & 63;
    const int wave = tid >> 6;
    const int fr   = lane & 15;
    const int fq   = lane >> 4;

    {
        constexpr int TOTAL = ROWS_B * CHUNKS_PER_ROW;   // 768
        #pragma unroll
        for (int c0 = 0; c0 < TOTAL; c0 += 512) {
            int c = c0 + tid;
            if (c >= TOTAL) break;
            int r = c / CHUNKS_PER_ROW;
            int w = c - r * CHUNKS_PER_ROW;
            short8v v = *(const short8v*)(Wt + (size_t)r * KT + w * 8);
            int dstByte = r * ROW_BYTES + ((w * 16) ^ ((r & 7) << 4));
            *(short8v*)(lds + dstByte) = v;
        }
    }
    __syncthreads();

    const int rowblk = blockIdx.x * 128 + wave * 16;

    short8v aReg[KSTEPS];
    {
        int r = rowblk + fr;
        if (r >= M) r = M - 1;
        #pragma unroll
        for (int ks = 0; ks < KSTEPS; ++ks)
            aReg[ks] = *(const short8v*)(A + (size_t)r * KT + ks * 32 + fq * 8);
    }

    f32x4 acc[NT];
    #pragma unroll
    for (int n = 0; n < NT; ++n) acc[n] = (f32x4){0.f, 0.f, 0.f, 0.f};

    #pragma unroll
    for (int ks = 0; ks < KSTEPS; ++ks) {
        const int kByte = ks * 64 + fq * 16;
        short8v b[NT];
        #pragma unroll
        for (int n = 0; n < NT; ++n) {
            int lr = n * 16 + fr;
            b[n] = *(const short8v*)(lds + lr * ROW_BYTES + (kByte ^ ((lr & 7) << 4)));
        }
        #pragma unroll
        for (int n = 0; n < NT; ++n)
            acc[n] = __builtin_amdgcn_mfma_f32_16x16x32_bf16(aReg[ks], b[n], acc[n], 0, 0, 0);
    }

    float bv0 = bias[fr];
    float bv1 = bias[16 + fr];
    float bv2 = (fr < 8) ? bias[32 + fr] : 0.f;
    const float NEG = -3.402823466e38f;

    #pragma unroll
    for (int j = 0; j < 4; ++j) {
        int row = rowblk + fq * 4 + j;
        float v0 = acc[0][j] + bv0;
        float v1 = acc[1][j] + bv1;
        float v2 = (fr < 8) ? (acc[2][j] + bv2) : NEG;
        float m = fmaxf(fmaxf(v0, v1), v2);
        #pragma unroll
        for (int off = 1; off < 16; off <<= 1) m = fmaxf(m, __shfl_xor(m, off, 64));
        float s = expf(v0 - m) + expf(v1 - m) + ((fr < 8) ? expf(v2 - m) : 0.f);
        #pragma unroll
        for (int off = 1; off < 16; off <<= 1) s += __shfl_xor(s, off, 64);
        float ls = m + logf(s);
        if (row < M) {
            out[(size_t)row * 40 + fr]      = v0 - ls;
            out[(size_t)row * 40 + 16 + fr] = v1 - ls;
            if (fr < 8) out[(size_t)row * 40 + 32 + fr] = v2 - ls;
        }
    }
}

// ---------------------------------------------------------------------------
// CSR build (R4-verified logic, fewer dispatches)
// ---------------------------------------------------------------------------
__global__ __launch_bounds__(256) void degree_kernel(
    const int* __restrict__ dst, int* __restrict__ cnt, int E)
{
    int e = blockIdx.x * 256 + threadIdx.x;
    if (e < E) atomicAdd(&cnt[dst[e]], 1);
}

__global__ __launch_bounds__(256) void scan_block_kernel(
    const int* __restrict__ cnt, int* __restrict__ rs,
    int* __restrict__ partials, int N)
{
    __shared__ int sm[256];
    int i = blockIdx.x * 256 + threadIdx.x;
    int v = (i < N) ? cnt[i] : 0;
    sm[threadIdx.x] = v;
    __syncthreads();
    #pragma unroll
    for (int off = 1; off < 256; off <<= 1) {
        int t = (threadIdx.x >= off) ? sm[threadIdx.x - off] : 0;
        __syncthreads();
        sm[threadIdx.x] += t;
        __syncthreads();
    }
    if (i < N) rs[i] = sm[threadIdx.x] - v;
    if (threadIdx.x == 255) partials[blockIdx.x] = sm[255];
}

// inline partials-scan + offset add + cursor copy (cnt <- rs) in one pass
__global__ __launch_bounds__(512) void add_offsets2_kernel(
    int* __restrict__ rs, const int* __restrict__ partials,
    int* __restrict__ cursor, int N, int E, int nblk)
{
    __shared__ int sm[512];
    int v = (threadIdx.x < nblk) ? partials[threadIdx.x] : 0;
    sm[threadIdx.x] = v;
    __syncthreads();
    #pragma unroll
    for (int off = 1; off < 512; off <<= 1) {
        int t = (threadIdx.x >= off) ? sm[threadIdx.x - off] : 0;
        __syncthreads();
        sm[threadIdx.x] += t;
        __syncthreads();
    }
    int excl = sm[threadIdx.x] - v;
    __syncthreads();
    sm[threadIdx.x] = excl;
    __syncthreads();
    int i = blockIdx.x * 512 + threadIdx.x;
    if (i < N) {
        int r2 = rs[i] + sm[i >> 8];
        rs[i] = r2;
        cursor[i] = r2;
    }
    if (i == N) rs[N] = E;
}

__global__ __launch_bounds__(256) void fill_kernel(
    const int* __restrict__ src, const int* __restrict__ dst,
    int* __restrict__ cursor, int* __restrict__ csr_src, int E)
{
    int e = blockIdx.x * 256 + threadIdx.x;
    if (e >= E) return;
    int d = dst[e];
    int pos = atomicAdd(&cursor[d], 1);
    csr_src[pos] = src[e];
}

// ---------------------------------------------------------------------------
extern "C" void kernel_launch(void* const* d_in, const int* in_sizes, int n_in,
                              void* d_out, int out_size, void* d_ws, size_t ws_size,
                              hipStream_t stream)
{
    const float* x      = (const float*)d_in[0];
    const int*   edge   = (const int*)d_in[1];
    const float* enc_w1 = (const float*)d_in[2];
    const float* enc_b1 = (const float*)d_in[3];
    const float* enc_w2 = (const float*)d_in[4];
    const float* enc_b2 = (const float*)d_in[5];
    const float* gcn_w  = (const float*)d_in[6];
    const float* gcn_b  = (const float*)d_in[7];
    const float* dec_w1 = (const float*)d_in[8];
    const float* dec_b1 = (const float*)d_in[9];
    const float* dec_w2 = (const float*)d_in[10];
    const float* dec_b2 = (const float*)d_in[11];

    const int F_IN = 128, R = 3;
    const int N = in_sizes[0] / F_IN;   // 100000
    const int E = in_sizes[1] / 2;      // 600000
    const int* src = edge;
    const int* dst = edge + E;

    // ---- workspace layout ----
    char* p = (char*)d_ws;
    ushort* h1    = (ushort*)p;                  p += (size_t)N * 256 * 2;  // 51.2 MB
    ushort* hA    = (ushort*)p;                  p += (size_t)N * 128 * 2;  // 25.6 MB
    ushort* hB    = (ushort*)p;                  p += (size_t)N * 128 * 2;  // 25.6 MB
    ushort* arena = (ushort*)p;                  p += 137216 * 2;           // weights
    int* csr_src  = (int*)p;                     p += (size_t)E * 4;
    int* rs       = (int*)p;                     p += (size_t)(N + 1) * 4;
    int* cnt      = (int*)p;                     p += (size_t)N * 4;
    int* partials = (int*)p;

    const ushort* enc1t = arena;
    const ushort* enc2t = arena + 32768;
    const ushort* gcnt  = arena + 65536;
    const ushort* dec1t = arena + 114688;
    const ushort* dec2t = arena + 131072;

    float* out = (float*)d_out;
    dim3 blk(256);
    dim3 blk512(512);

    // 1: all weight transposes
    wtrans_all_kernel<<<dim3(128, 7), blk, 0, stream>>>(
        enc_w1, enc_w2, gcn_w, dec_w1, dec_w2, arena);

    // CSR build (5 dispatches incl. memset)
    const int nblkN = (N + 255) / 256;   // 391
    const int nblkE = (E + 255) / 256;
    hipMemsetAsync(cnt, 0, (size_t)N * sizeof(int), stream);
    degree_kernel<<<nblkE, blk, 0, stream>>>(dst, cnt, E);
    scan_block_kernel<<<nblkN, blk, 0, stream>>>(cnt, rs, partials, N);
    add_offsets2_kernel<<<(N + 1 + 511) / 512, blk512, 0, stream>>>(
        rs, partials, cnt, N, E, nblkN);
    fill_kernel<<<nblkE, blk, 0, stream>>>(src, dst, cnt, csr_src, E);

    const int gdx = (N + 127) / 128;   // 782

    // encoder (enc1 reads f32 x directly)
    dense_mfma5_kernel<true, 8, 128, true, true><<<dim3(gdx, 2), blk512, 0, stream>>>(
        x, enc1t, enc_b1, h1, N, 256);
    dense_mfma5_kernel<false, 4, 256, false, true><<<dim3(gdx, 2), blk512, 0, stream>>>(
        h1, enc2t, enc_b2, hA, N, 128);

    // 3 fused GCN hops (gather-agg + transform + bias + relu)
    ushort* cur = hA;
    ushort* nxt = hB;
    for (int r = 0; r < R; ++r) {
        gcn_hop_kernel<<<gdx, blk512, 0, stream>>>(
            cur, gcnt + (size_t)r * 16384, csr_src, rs, gcn_b + (size_t)r * 128, nxt, N);
        ushort* t = cur; cur = nxt; nxt = t;
    }

    // decoder (dec2 + log_softmax fused)
    dense_mfma5_kernel<true, 8, 128, false, true><<<dim3(gdx, 1), blk512, 0, stream>>>(
        cur, dec1t, dec_b1, nxt, N, 128);
    dense_dec2sm_kernel<<<gdx, blk512, 0, stream>>>(
        nxt, dec2t, dec_b2, out, N);
}